// Round 2
// baseline (1674.070 us; speedup 1.0000x reference)
//
#include <hip/hip_runtime.h>
#include <cstdint>
#include <cstddef>
#include <cmath>

#define D 256
#define H 4
#define LN_EPS 1e-5f
#define SPAD 512
#define NMAT 13
#define PBS 520   // Pb row stride in shorts: 1040 B = 65*16 (aligned), 260 words
#define LOG2E 1.44269504088896340736f

typedef __attribute__((ext_vector_type(8))) short short8;
typedef __attribute__((ext_vector_type(4))) short short4v;
typedef __attribute__((ext_vector_type(4))) float f32x4;
typedef __attribute__((ext_vector_type(2))) float f32x2;

static __device__ __forceinline__ short f2bf(float f) {
    union { float f; unsigned u; } a; a.f = f;
    unsigned r = a.u + 0x7fffu + ((a.u >> 16) & 1u);
    return (short)(r >> 16);
}

static __device__ __forceinline__ float exp2_fast(float x) {
#if __has_builtin(__builtin_amdgcn_exp2f)
    return __builtin_amdgcn_exp2f(x);
#else
    float r; asm("v_exp_f32 %0, %1" : "=v"(r) : "v"(x)); return r;
#endif
}

// ---------- pack fp32 W[k][n] -> bf16 fragment-ordered B ----------
struct PackArgs { const float* src[NMAT]; float scale[NMAT]; short* dst; };

__global__ __launch_bounds__(256)
void pack_kernel(PackArgs pa)
{
    const int mat = blockIdx.y;
    const int el = blockIdx.x * 256 + threadIdx.x;
    const int n = el & 255, k = el >> 8;
    const int nt = n >> 4, l16 = n & 15;
    const int kc = k >> 5, qd = (k >> 3) & 3, j = k & 7;
    const size_t didx = (((size_t)(kc * 16 + nt) * 64) + qd * 16 + l16) * 8 + j;
    pa.dst[(size_t)mat * 65536 + didx] =
        f2bf(pa.src[mat][(size_t)k * 256 + n] * pa.scale[mat]);
}

// ---------- gate table: gtab[l][h][q][pos] = tanh(attn_w[l][h][cat(q,key(pos))]) ----------
// pos is the PERMUTED key index: within each 32-block, key = 16*(pos&1) + ((pos>>1)&15).
__global__ __launch_bounds__(256)
void gate_tab_kernel(const float* __restrict__ aw, const int* __restrict__ Kp,
                     float* __restrict__ gt, int S)
{
    const int idx = blockIdx.x * 256 + threadIdx.x;   // [0, 512*512)
    const int h = blockIdx.y, l = blockIdx.z;
    const int q = idx >> 9, pos = idx & 511;
    const int key = (pos & ~31) | ((pos & 1) << 4) | ((pos >> 1) & 15);
    const int NK = S - 1;
    const int Kc = Kp[0];
    int cat = 2;
    if (q < NK) {
        if (key == NK) cat = 3;
        else if (key < NK && (q / Kc) == (key / Kc)) cat = 1;
        if (key == q) cat = 0;
    } else if (q == NK) {
        cat = (key == NK) ? 5 : (key < NK ? 4 : 2);
    }
    gt[(((size_t)l * H + h) << 18) + ((size_t)q << 9) + pos] =
        tanhf(aw[(l * H + h) * 6 + cat]);
}

// ---------- fused fp32 copy + bf16 cast ----------
__global__ __launch_bounds__(256)
void copy_cast_kernel(const float* __restrict__ x, float* __restrict__ xc,
                      short* __restrict__ xb, long n)
{
    const long i = ((long)blockIdx.x * 256 + threadIdx.x) * 4;
    if (i >= n) return;
    const f32x4 v = *(const f32x4*)(x + i);
    *(f32x4*)(xc + i) = v;
    short4v o;
    o.x = f2bf(v.x); o.y = f2bf(v.y); o.z = f2bf(v.z); o.w = f2bf(v.w);
    *(short4v*)(xb + i) = o;
}

// ---------- MFMA mainloop: 16 rows x 256 cols per wave, K=256 ----------
// A fragments hoisted (32 VGPRs) so B loads can pipeline ahead under the
// 128-VGPR budget from __launch_bounds__(256,4).
static __device__ __forceinline__ void gemm_tile(const short* __restrict__ A,
                                                 const short* __restrict__ Bt,
                                                 int rowA, int lane, int quad,
                                                 f32x4 (&acc)[16])
{
    const short* Ar = A + (size_t)rowA * D + quad * 8;
    const short* Bl = Bt + (size_t)lane * 8;
    short8 af[8];
    #pragma unroll
    for (int kc = 0; kc < 8; ++kc) af[kc] = *(const short8*)(Ar + kc * 32);
    #pragma unroll
    for (int nt = 0; nt < 16; ++nt) acc[nt] = (f32x4){0.f, 0.f, 0.f, 0.f};
    #pragma unroll
    for (int kc = 0; kc < 8; ++kc) {
        #pragma unroll
        for (int nt = 0; nt < 16; ++nt) {
            const short8 bf = *(const short8*)(Bl + (size_t)(kc * 16 + nt) * 512);
            acc[nt] = __builtin_amdgcn_mfma_f32_16x16x32_bf16(af[kc], bf, acc[nt], 0, 0, 0);
        }
    }
}

// ---------- GEMM + bias + residual + LayerNorm, writes fp32 + bf16 ----------
__global__ __launch_bounds__(256, 4)
void gemm_res_ln_kernel(const short* __restrict__ A, const short* __restrict__ Bt,
                        const float* __restrict__ bias, const float* __restrict__ resid,
                        const float* __restrict__ gam, const float* __restrict__ bet,
                        float* __restrict__ xout, short* __restrict__ xbout)
{
    const int tid = threadIdx.x, wave = tid >> 6, lane = tid & 63;
    const int l16 = lane & 15, quad = lane >> 4;
    const int row0 = blockIdx.x * 64 + wave * 16;
    f32x4 acc[16];
    gemm_tile(A, Bt, row0 + l16, lane, quad, acc);

    #pragma unroll
    for (int nt = 0; nt < 16; ++nt) {
        const int col = nt * 16 + l16;
        const float bl = bias[col];
        #pragma unroll
        for (int r = 0; r < 4; ++r)
            acc[nt][r] += bl + resid[(size_t)(row0 + quad * 4 + r) * D + col];
    }
    float mu[4], rstd[4];
    #pragma unroll
    for (int r = 0; r < 4; ++r) {
        float s = 0.f;
        #pragma unroll
        for (int nt = 0; nt < 16; ++nt) s += acc[nt][r];
        s += __shfl_xor(s, 1, 64); s += __shfl_xor(s, 2, 64);
        s += __shfl_xor(s, 4, 64); s += __shfl_xor(s, 8, 64);
        mu[r] = s * (1.f / D);
        float q = 0.f;
        #pragma unroll
        for (int nt = 0; nt < 16; ++nt) { const float d = acc[nt][r] - mu[r]; q = fmaf(d, d, q); }
        q += __shfl_xor(q, 1, 64); q += __shfl_xor(q, 2, 64);
        q += __shfl_xor(q, 4, 64); q += __shfl_xor(q, 8, 64);
        rstd[r] = rsqrtf(q * (1.f / D) + LN_EPS);
    }
    #pragma unroll
    for (int nt = 0; nt < 16; ++nt) {
        const int col = nt * 16 + l16;
        const float g = gam[col], be = bet[col];
        #pragma unroll
        for (int r = 0; r < 4; ++r) {
            const size_t idx = (size_t)(row0 + quad * 4 + r) * D + col;
            const float o = (acc[nt][r] - mu[r]) * rstd[r] * g + be;
            xout[idx] = o;
            xbout[idx] = f2bf(o);
        }
    }
}

// ---------- GEMM + bias + relu -> bf16 ----------
__global__ __launch_bounds__(256, 4)
void gemm_relu_kernel(const short* __restrict__ A, const short* __restrict__ Bt,
                      const float* __restrict__ bias, short* __restrict__ hb)
{
    const int tid = threadIdx.x, wave = tid >> 6, lane = tid & 63;
    const int l16 = lane & 15, quad = lane >> 4;
    const int row0 = blockIdx.x * 64 + wave * 16;
    f32x4 acc[16];
    gemm_tile(A, Bt, row0 + l16, lane, quad, acc);
    #pragma unroll
    for (int nt = 0; nt < 16; ++nt) {
        const int col = nt * 16 + l16;
        const float bl = bias[col];
        #pragma unroll
        for (int r = 0; r < 4; ++r)
            hb[(size_t)(row0 + quad * 4 + r) * D + col] = f2bf(fmaxf(acc[nt][r] + bl, 0.f));
    }
}

// ---------- QKV: three GEMMs, writes Q,K (padded) + V^T (key-permuted) ----------
__global__ __launch_bounds__(256, 4)
void qkv_gemm_kernel(const short* __restrict__ A, const short* __restrict__ Wt,
                     short* __restrict__ Qb, short* __restrict__ Kb,
                     short* __restrict__ Vt, int S)
{
    const int tid = threadIdx.x, wave = tid >> 6, lane = tid & 63;
    const int l16 = lane & 15, quad = lane >> 4;
    const int row0 = blockIdx.x * 64 + wave * 16;
    int bb[4], ss[4];
    #pragma unroll
    for (int r = 0; r < 4; ++r) {
        const int row = row0 + quad * 4 + r;
        bb[r] = row / S; ss[r] = row - bb[r] * S;
    }
    #pragma unroll 1
    for (int m = 0; m < 3; ++m) {
        f32x4 acc[16];
        gemm_tile(A, Wt + (size_t)m * 65536, row0 + l16, lane, quad, acc);
        #pragma unroll
        for (int nt = 0; nt < 16; ++nt) {
            const int col = nt * 16 + l16, h = col >> 6, dim = col & 63;
            #pragma unroll
            for (int r = 0; r < 4; ++r) {
                const int bh = bb[r] * H + h;
                const short v = f2bf(acc[nt][r]);
                if (m == 0)      Qb[((size_t)bh * SPAD + ss[r]) * 64 + dim] = v;
                else if (m == 1) Kb[((size_t)bh * SPAD + ss[r]) * 64 + dim] = v;
                else {
                    // permuted key position: pos = 2*(s&15) + ((s>>4)&1) within 32-block
                    const int sp = (ss[r] & ~31) | ((ss[r] & 15) << 1) | ((ss[r] >> 4) & 1);
                    Vt[((size_t)bh * 64 + dim) * SPAD + sp] = v;
                }
            }
        }
    }
}

// ---------------- MFMA attention: deep-prefetch, no-max softmax, table gate ----------------
// Wq prescaled by log2e/temperature so exp is a single v_exp_f32 (2^x domain).
// grid = dim3(8, qt, B*H/8). Wave w: QK for keys [w*128,w*128+128); one barrier;
// PV for d-slice [w*16,w*16+16) over all 512 (permuted) key positions.
// __launch_bounds__(256,4): 128-VGPR budget so ALL K-frags (64 regs) + gate
// words (32 regs) are prefetched before the MFMA block — loads pipeline instead
// of serializing one vmcnt(0) at a time (round-1 failure mode at VGPR=44).
__global__ __launch_bounds__(256, 4)
void attn_kernel(const short* __restrict__ Qb, const short* __restrict__ Kb,
                 const short* __restrict__ Vt, const float* __restrict__ gt,
                 short* __restrict__ out, int S)
{
    const int bh = blockIdx.z * 8 + blockIdx.x;
    const int b = bh >> 2, h = bh & 3;
    const int q0 = blockIdx.y << 4;
    const int tid = threadIdx.x;
    const int wave = tid >> 6, lane = tid & 63;
    const int l16 = lane & 15, quad = lane >> 4;

    __shared__ __align__(16) float Lw[16][4];
    __shared__ __align__(16) short Pb[16][PBS];   // [q][pos], 512 permuted keys

    const int kb0 = wave * 128;
    const short* Kbh = Kb + (size_t)bh * SPAD * 64;
    const short* Vbh = Vt + (size_t)bh * 64 * SPAD;

    // ---- issue ALL loads for phase 1 up front: Q, 16 K-frags, 16 gate words ----
    const size_t qrow = ((size_t)bh * SPAD + q0 + l16) * 64;
    const short8 aq0 = *(const short8*)(Qb + qrow + quad * 8);
    const short8 aq1 = *(const short8*)(Qb + qrow + 32 + quad * 8);

    short8 kf[16];
    #pragma unroll
    for (int c = 0; c < 4; ++c) {
        const size_t kr = (size_t)(kb0 + c * 32 + l16) * 64 + quad * 8;
        kf[4 * c + 0] = *(const short8*)(Kbh + kr);
        kf[4 * c + 1] = *(const short8*)(Kbh + kr + 32);
        kf[4 * c + 2] = *(const short8*)(Kbh + kr + 16 * 64);
        kf[4 * c + 3] = *(const short8*)(Kbh + kr + 16 * 64 + 32);
    }

    f32x2 gpre[16];   // gate words, consumed in phase 3 — issued early to overlap
    const float* gbase = gt + (((size_t)h) << 18) +
                         (((size_t)(q0 + quad * 4)) << 9) + kb0 + 2 * l16;
    #pragma unroll
    for (int r = 0; r < 4; ++r)
        #pragma unroll
        for (int c = 0; c < 4; ++c)
            gpre[r * 4 + c] = *(const f32x2*)(gbase + ((size_t)r << 9) + c * 32);

    // ---- phase 1: QK^T scores, 8 independent accumulator chains ----
    f32x4 sc[8];
    #pragma unroll
    for (int c = 0; c < 4; ++c) {
        const int kbase = kb0 + c * 32;
        f32x4 s0 = (f32x4){0.f, 0.f, 0.f, 0.f}, s1 = (f32x4){0.f, 0.f, 0.f, 0.f};
        s0 = __builtin_amdgcn_mfma_f32_16x16x32_bf16(aq0, kf[4 * c + 0], s0, 0, 0, 0);
        s0 = __builtin_amdgcn_mfma_f32_16x16x32_bf16(aq1, kf[4 * c + 1], s0, 0, 0, 0);
        s1 = __builtin_amdgcn_mfma_f32_16x16x32_bf16(aq0, kf[4 * c + 2], s1, 0, 0, 0);
        s1 = __builtin_amdgcn_mfma_f32_16x16x32_bf16(aq1, kf[4 * c + 3], s1, 0, 0, 0);
        if (kbase + 32 > S) {
            const bool v0 = (kbase + l16) < S, v1 = (kbase + 16 + l16) < S;
            #pragma unroll
            for (int r = 0; r < 4; ++r) {
                s0[r] = v0 ? s0[r] : -INFINITY;
                s1[r] = v1 ? s1[r] : -INFINITY;
            }
        }
        sc[2 * c] = s0; sc[2 * c + 1] = s1;
    }

    // ---- phase 2: exp2 + row sums ----
    float ls[4] = {0.f, 0.f, 0.f, 0.f};
    #pragma unroll
    for (int j = 0; j < 8; ++j) {
        #pragma unroll
        for (int r = 0; r < 4; ++r) {
            const float e = exp2_fast(sc[j][r]);
            sc[j][r] = e;
            ls[r] += e;
        }
    }
    #pragma unroll
    for (int r = 0; r < 4; ++r) {
        ls[r] += __shfl_xor(ls[r], 1, 64);
        ls[r] += __shfl_xor(ls[r], 2, 64);
        ls[r] += __shfl_xor(ls[r], 4, 64);
        ls[r] += __shfl_xor(ls[r], 8, 64);
    }
    if (l16 == 0) {
        #pragma unroll
        for (int r = 0; r < 4; ++r) Lw[quad * 4 + r][wave] = ls[r];
    }

    // ---- phase 3: table gate + cvt_pk -> packed b32 P writes (permuted layout) ----
    #pragma unroll
    for (int c = 0; c < 4; ++c) {
        #pragma unroll
        for (int r = 0; r < 4; ++r) {
            const f32x2 g = gpre[r * 4 + c];
            const float p0 = sc[2 * c][r] * g.x;
            const float p1 = sc[2 * c + 1][r] * g.y;
            unsigned int pk;
            asm("v_cvt_pk_bf16_f32 %0, %1, %2" : "=v"(pk) : "v"(p0), "v"(p1));
            *(unsigned int*)(&Pb[quad * 4 + r][kb0 + c * 32 + 2 * l16]) = pk;
        }
    }
    __syncthreads();

    // ---- phase 4: PV, two 8-deep load batches, two accumulator chains ----
    const int dsl = wave * 16;
    const short* Vrow = Vbh + (size_t)(dsl + l16) * SPAD + quad * 8;
    const short* Prow = &Pb[l16][quad * 8];
    f32x4 O0 = (f32x4){0.f, 0.f, 0.f, 0.f}, O1 = (f32x4){0.f, 0.f, 0.f, 0.f};
    #pragma unroll
    for (int g = 0; g < 2; ++g) {
        short8 ap[8], vf[8];
        #pragma unroll
        for (int j = 0; j < 8; ++j) {
            const int ks = g * 8 + j;
            ap[j] = *(const short8*)(Prow + ks * 32);
            vf[j] = *(const short8*)(Vrow + ks * 32);
        }
        #pragma unroll
        for (int j = 0; j < 8; j += 2) {
            O0 = __builtin_amdgcn_mfma_f32_16x16x32_bf16(ap[j], vf[j], O0, 0, 0, 0);
            O1 = __builtin_amdgcn_mfma_f32_16x16x32_bf16(ap[j + 1], vf[j + 1], O1, 0, 0, 0);
        }
    }
    const f32x4 O = O0 + O1;

    // ---- epilogue: divide by global l, write bf16 ----
    #pragma unroll
    for (int r = 0; r < 4; ++r) {
        const int q = quad * 4 + r;
        const int s = q0 + q;
        if (s < S) {
            const f32x4 lv = *(const f32x4*)Lw[q];
            const float lq = (lv[0] + lv[1]) + (lv[2] + lv[3]);
            out[((size_t)b * S + s) * D + h * 64 + dsl + l16] =
                f2bf(O[r] * __builtin_amdgcn_rcpf(lq));
        }
    }
}

extern "C" void kernel_launch(void* const* d_in, const int* in_sizes, int n_in,
                              void* d_out, int out_size, void* d_ws, size_t ws_size,
                              hipStream_t stream)
{
    const float* samples = (const float*)d_in[0];
    const float* Wq      = (const float*)d_in[1];
    const float* Wk      = (const float*)d_in[2];
    const float* Wv      = (const float*)d_in[3];
    const float* attn_w  = (const float*)d_in[4];
    const float* fc_w    = (const float*)d_in[5];
    const float* fc_b    = (const float*)d_in[6];
    const float* mha_g   = (const float*)d_in[7];
    const float* mha_b   = (const float*)d_in[8];
    const float* w1      = (const float*)d_in[9];
    const float* b1      = (const float*)d_in[10];
    const float* w2      = (const float*)d_in[11];
    const float* b2      = (const float*)d_in[12];
    const float* dg      = (const float*)d_in[13];
    const float* db      = (const float*)d_in[14];
    const float* ow      = (const float*)d_in[15];
    const float* ob      = (const float*)d_in[16];
    const float* og      = (const float*)d_in[17];
    const float* obeta   = (const float*)d_in[18];
    const int*   Kp      = (const int*)d_in[20];

    const int Bsz = 128;
    const int S = in_sizes[0] / (Bsz * D);   // 501
    const int rows = Bsz * S;                // 64128
    const size_t n_el = (size_t)rows * D;
    const size_t n_pad = (size_t)Bsz * H * SPAD * 64;

    float* x   = (float*)d_out;
    short* xb  = (short*)d_ws;               // bf16 activations [rows][D]
    short* aob = xb + n_el;                  // attn out bf16; later reused as hb
    short* hb  = aob;
    short* Qb  = aob + n_el;                 // [B*H][512][64]
    short* Kb  = Qb + n_pad;                 // [B*H][512][64]
    short* Vt  = Kb + n_pad;                 // [B*H][64][512] (key-permuted)
    short* wts = Vt + n_pad;
    float* gtab = (float*)(wts + (size_t)NMAT * 65536);   // [L][H][512][512] f32, 8.4 MB

    PackArgs pa;
    for (int l = 0; l < 2; ++l) {
        const size_t wo = (size_t)l * 65536;
        pa.src[l*6 + 0] = Wq + wo;   pa.scale[l*6 + 0] = 0.125f * LOG2E;  // temp + log2e fold
        pa.src[l*6 + 1] = Wk + wo;   pa.scale[l*6 + 1] = 1.f;
        pa.src[l*6 + 2] = Wv + wo;   pa.scale[l*6 + 2] = 1.f;
        pa.src[l*6 + 3] = fc_w + wo; pa.scale[l*6 + 3] = 1.f;
        pa.src[l*6 + 4] = w1 + wo;   pa.scale[l*6 + 4] = 1.f;
        pa.src[l*6 + 5] = w2 + wo;   pa.scale[l*6 + 5] = 1.f;
    }
    pa.src[12] = ow; pa.scale[12] = 1.f;
    pa.dst = wts;
    pack_kernel<<<dim3(256, NMAT), 256, 0, stream>>>(pa);

    gate_tab_kernel<<<dim3(1024, H, 2), 256, 0, stream>>>(attn_w, Kp, gtab, S);

    copy_cast_kernel<<<(int)((n_el / 4 + 255) / 256), 256, 0, stream>>>(samples, x, xb, (long)n_el);

    const int gblocks = rows / 64;           // 1002
    const int qt = (S + 15) / 16;            // 32
    for (int l = 0; l < 2; ++l) {
        short* wl = wts + (size_t)l * 6 * 65536;
        qkv_gemm_kernel<<<gblocks, 256, 0, stream>>>(xb, wl, Qb, Kb, Vt, S);
        attn_kernel<<<dim3(8, qt, Bsz * H / 8), 256, 0, stream>>>(Qb, Kb, Vt,
                                              gtab + ((size_t)l << 20), aob, S);
        gemm_res_ln_kernel<<<gblocks, 256, 0, stream>>>(aob, wl + 3 * 65536,
                                              fc_b + (size_t)l * D, x,
                                              mha_g + (size_t)l * D, mha_b + (size_t)l * D,
                                              x, xb);
        gemm_relu_kernel<<<gblocks, 256, 0, stream>>>(xb, wl + 4 * 65536,
                                              b1 + (size_t)l * D, hb);
        gemm_res_ln_kernel<<<gblocks, 256, 0, stream>>>(hb, wl + 5 * 65536,
                                              b2 + (size_t)l * D, x,
                                              dg + (size_t)l * D, db + (size_t)l * D,
                                              x, xb);
    }
    gemm_res_ln_kernel<<<gblocks, 256, 0, stream>>>(xb, wts + 12 * 65536,
                                              ob, samples, og, obeta, x, xb);
}

// Round 3
// 1335.099 us; speedup vs baseline: 1.2539x; 1.2539x over previous
//
#include <hip/hip_runtime.h>
#include <cstdint>
#include <cstddef>
#include <cmath>

#define D 256
#define H 4
#define LN_EPS 1e-5f
#define SPAD 512
#define NMAT 13
#define PBS 520   // Pb row stride in shorts: 1040 B = 65*16 (aligned), 260 words
#define LOG2E 1.44269504088896340736f

typedef __attribute__((ext_vector_type(8))) short short8;
typedef __attribute__((ext_vector_type(4))) short short4v;
typedef __attribute__((ext_vector_type(4))) float f32x4;
typedef __attribute__((ext_vector_type(2))) float f32x2;
typedef __attribute__((ext_vector_type(4))) int i32x4;

#define KEEP(x) asm volatile("" :: "v"(x))

static __device__ __forceinline__ short f2bf(float f) {
    union { float f; unsigned u; } a; a.f = f;
    unsigned r = a.u + 0x7fffu + ((a.u >> 16) & 1u);
    return (short)(r >> 16);
}

static __device__ __forceinline__ float exp2_fast(float x) {
#if __has_builtin(__builtin_amdgcn_exp2f)
    return __builtin_amdgcn_exp2f(x);
#else
    float r; asm("v_exp_f32 %0, %1" : "=v"(r) : "v"(x)); return r;
#endif
}

// ---------- pack fp32 W[k][n] -> bf16 fragment-ordered B ----------
struct PackArgs { const float* src[NMAT]; float scale[NMAT]; short* dst; };

__global__ __launch_bounds__(256)
void pack_kernel(PackArgs pa)
{
    const int mat = blockIdx.y;
    const int el = blockIdx.x * 256 + threadIdx.x;
    const int n = el & 255, k = el >> 8;
    const int nt = n >> 4, l16 = n & 15;
    const int kc = k >> 5, qd = (k >> 3) & 3, j = k & 7;
    const size_t didx = (((size_t)(kc * 16 + nt) * 64) + qd * 16 + l16) * 8 + j;
    pa.dst[(size_t)mat * 65536 + didx] =
        f2bf(pa.src[mat][(size_t)k * 256 + n] * pa.scale[mat]);
}

// ---------- gate table: gtab[l][h][q][pos] = tanh(attn_w[l][h][cat(q,key(pos))]) ----------
// pos is the PERMUTED key index: within each 32-block, key = 16*(pos&1) + ((pos>>1)&15).
__global__ __launch_bounds__(256)
void gate_tab_kernel(const float* __restrict__ aw, const int* __restrict__ Kp,
                     float* __restrict__ gt, int S)
{
    const int idx = blockIdx.x * 256 + threadIdx.x;   // [0, 512*512)
    const int h = blockIdx.y, l = blockIdx.z;
    const int q = idx >> 9, pos = idx & 511;
    const int key = (pos & ~31) | ((pos & 1) << 4) | ((pos >> 1) & 15);
    const int NK = S - 1;
    const int Kc = Kp[0];
    int cat = 2;
    if (q < NK) {
        if (key == NK) cat = 3;
        else if (key < NK && (q / Kc) == (key / Kc)) cat = 1;
        if (key == q) cat = 0;
    } else if (q == NK) {
        cat = (key == NK) ? 5 : (key < NK ? 4 : 2);
    }
    gt[(((size_t)l * H + h) << 18) + ((size_t)q << 9) + pos] =
        tanhf(aw[(l * H + h) * 6 + cat]);
}

// ---------- fused fp32 copy + bf16 cast ----------
__global__ __launch_bounds__(256)
void copy_cast_kernel(const float* __restrict__ x, float* __restrict__ xc,
                      short* __restrict__ xb, long n)
{
    const long i = ((long)blockIdx.x * 256 + threadIdx.x) * 4;
    if (i >= n) return;
    const f32x4 v = *(const f32x4*)(x + i);
    *(f32x4*)(xc + i) = v;
    short4v o;
    o.x = f2bf(v.x); o.y = f2bf(v.y); o.z = f2bf(v.z); o.w = f2bf(v.w);
    *(short4v*)(xb + i) = o;
}

// ---------- MFMA mainloop (round-1 form): 16 rows x 256 cols per wave, K=256 ----------
static __device__ __forceinline__ void gemm_tile(const short* __restrict__ A,
                                                 const short* __restrict__ Bt,
                                                 int rowA, int lane, int quad,
                                                 f32x4 (&acc)[16])
{
    const short* Ar = A + (size_t)rowA * D + quad * 8;
    const short* Bl = Bt + (size_t)lane * 8;
    #pragma unroll
    for (int nt = 0; nt < 16; ++nt) acc[nt] = (f32x4){0.f, 0.f, 0.f, 0.f};
    #pragma unroll
    for (int kc = 0; kc < 8; ++kc) {
        const short8 af = *(const short8*)(Ar + kc * 32);
        #pragma unroll
        for (int nt = 0; nt < 16; ++nt) {
            const short8 bf = *(const short8*)(Bl + (size_t)(kc * 16 + nt) * 512);
            acc[nt] = __builtin_amdgcn_mfma_f32_16x16x32_bf16(af, bf, acc[nt], 0, 0, 0);
        }
    }
}

// ---------- GEMM + bias + residual + LayerNorm, writes fp32 + bf16 ----------
__global__ __launch_bounds__(256)
void gemm_res_ln_kernel(const short* __restrict__ A, const short* __restrict__ Bt,
                        const float* __restrict__ bias, const float* __restrict__ resid,
                        const float* __restrict__ gam, const float* __restrict__ bet,
                        float* __restrict__ xout, short* __restrict__ xbout)
{
    const int tid = threadIdx.x, wave = tid >> 6, lane = tid & 63;
    const int l16 = lane & 15, quad = lane >> 4;
    const int row0 = blockIdx.x * 64 + wave * 16;
    f32x4 acc[16];
    gemm_tile(A, Bt, row0 + l16, lane, quad, acc);

    #pragma unroll
    for (int nt = 0; nt < 16; ++nt) {
        const int col = nt * 16 + l16;
        const float bl = bias[col];
        #pragma unroll
        for (int r = 0; r < 4; ++r)
            acc[nt][r] += bl + resid[(size_t)(row0 + quad * 4 + r) * D + col];
    }
    float mu[4], rstd[4];
    #pragma unroll
    for (int r = 0; r < 4; ++r) {
        float s = 0.f;
        #pragma unroll
        for (int nt = 0; nt < 16; ++nt) s += acc[nt][r];
        s += __shfl_xor(s, 1, 64); s += __shfl_xor(s, 2, 64);
        s += __shfl_xor(s, 4, 64); s += __shfl_xor(s, 8, 64);
        mu[r] = s * (1.f / D);
        float q = 0.f;
        #pragma unroll
        for (int nt = 0; nt < 16; ++nt) { const float d = acc[nt][r] - mu[r]; q = fmaf(d, d, q); }
        q += __shfl_xor(q, 1, 64); q += __shfl_xor(q, 2, 64);
        q += __shfl_xor(q, 4, 64); q += __shfl_xor(q, 8, 64);
        rstd[r] = rsqrtf(q * (1.f / D) + LN_EPS);
    }
    #pragma unroll
    for (int nt = 0; nt < 16; ++nt) {
        const int col = nt * 16 + l16;
        const float g = gam[col], be = bet[col];
        #pragma unroll
        for (int r = 0; r < 4; ++r) {
            const size_t idx = (size_t)(row0 + quad * 4 + r) * D + col;
            const float o = (acc[nt][r] - mu[r]) * rstd[r] * g + be;
            xout[idx] = o;
            xbout[idx] = f2bf(o);
        }
    }
}

// ---------- GEMM + bias + relu -> bf16 ----------
__global__ __launch_bounds__(256)
void gemm_relu_kernel(const short* __restrict__ A, const short* __restrict__ Bt,
                      const float* __restrict__ bias, short* __restrict__ hb)
{
    const int tid = threadIdx.x, wave = tid >> 6, lane = tid & 63;
    const int l16 = lane & 15, quad = lane >> 4;
    const int row0 = blockIdx.x * 64 + wave * 16;
    f32x4 acc[16];
    gemm_tile(A, Bt, row0 + l16, lane, quad, acc);
    #pragma unroll
    for (int nt = 0; nt < 16; ++nt) {
        const int col = nt * 16 + l16;
        const float bl = bias[col];
        #pragma unroll
        for (int r = 0; r < 4; ++r)
            hb[(size_t)(row0 + quad * 4 + r) * D + col] = f2bf(fmaxf(acc[nt][r] + bl, 0.f));
    }
}

// ---------- QKV: three GEMMs. Q,K padded layouts; V ROW-MAJOR (coalesced) ----------
__global__ __launch_bounds__(256)
void qkv_gemm_kernel(const short* __restrict__ A, const short* __restrict__ Wt,
                     short* __restrict__ Qb, short* __restrict__ Kb,
                     short* __restrict__ Vb, int S)
{
    const int tid = threadIdx.x, wave = tid >> 6, lane = tid & 63;
    const int l16 = lane & 15, quad = lane >> 4;
    const int row0 = blockIdx.x * 64 + wave * 16;
    int bb[4], ss[4];
    #pragma unroll
    for (int r = 0; r < 4; ++r) {
        const int row = row0 + quad * 4 + r;
        bb[r] = row / S; ss[r] = row - bb[r] * S;
    }
    #pragma unroll 1
    for (int m = 0; m < 3; ++m) {
        f32x4 acc[16];
        gemm_tile(A, Wt + (size_t)m * 65536, row0 + l16, lane, quad, acc);
        #pragma unroll
        for (int nt = 0; nt < 16; ++nt) {
            const int col = nt * 16 + l16, h = col >> 6, dim = col & 63;
            #pragma unroll
            for (int r = 0; r < 4; ++r) {
                const int bh = bb[r] * H + h;
                const short v = f2bf(acc[nt][r]);
                if (m == 0)      Qb[((size_t)bh * SPAD + ss[r]) * 64 + dim] = v;
                else if (m == 1) Kb[((size_t)bh * SPAD + ss[r]) * 64 + dim] = v;
                else             Vb[((size_t)bh * S + ss[r]) * 64 + dim] = v;   // row-major, unpadded
            }
        }
    }
}

// ---------- V transpose: [bh][s][64] -> Vt[bh][64][pos] (permuted, padded, zero tail) ----------
// pos permutation within each 32-block: pos = 2*(s&15) + ((s>>4)&1); dword at pos 2d
// packs keys (k0, k0+16). Fully coalesced global read/write through a 64x64 LDS tile.
__global__ __launch_bounds__(256)
void vt_transpose_kernel(const short* __restrict__ Vb, short* __restrict__ Vt, int S)
{
    const int bh = blockIdx.y;
    const int s0 = blockIdx.x * 64;
    const int t = threadIdx.x;
    __shared__ short T[64][72];
    {
        const int r = t >> 2, c = (t & 3) * 16;
        const int s = s0 + r;
        short8 v0 = (short8){0,0,0,0,0,0,0,0}, v1 = (short8){0,0,0,0,0,0,0,0};
        if (s < S) {
            const short* src = Vb + ((size_t)bh * S + s) * 64 + c;
            v0 = *(const short8*)src;
            v1 = *(const short8*)(src + 8);
        }
        *(short8*)&T[r][c] = v0;
        *(short8*)&T[r][c + 8] = v1;
    }
    __syncthreads();
    {
        const int dim = t >> 2, g = t & 3;
        int w[8];
        #pragma unroll
        for (int j = 0; j < 8; ++j) {
            const int d = g * 8 + j;                       // dword index 0..31 in this 64-span
            const int k0 = ((d >> 4) << 5) | (d & 15);     // key row in tile (pair partner +16)
            const unsigned lo = (unsigned short)T[k0][dim];
            const unsigned hi = (unsigned short)T[k0 + 16][dim];
            w[j] = (int)(lo | (hi << 16));
        }
        int* dst = (int*)(Vt + ((size_t)bh * 64 + dim) * SPAD + s0) + g * 8;
        *(i32x4*)dst = (i32x4){w[0], w[1], w[2], w[3]};
        *(i32x4*)(dst + 4) = (i32x4){w[4], w[5], w[6], w[7]};
    }
}

// ---------------- MFMA attention: deep-prefetch, no-max softmax, table gate ----------------
// Wq prescaled by log2e/temperature so exp is a single v_exp_f32 (2^x domain).
// grid = dim3(8, qt, B*H/8). Wave w: QK for keys [w*128,w*128+128); one barrier;
// PV for d-slice [w*16,w*16+16) over all 512 (permuted) key positions.
// (256,3): 170-unified-reg budget so the 16 K-frag prefetch (64 regs) fits;
// gate loads issue after QK MFMAs (overlap exp/reduce); first 8 V-frags issue
// before the barrier. KEEP() pins prefetches against allocator re-sinking.
__global__ __launch_bounds__(256, 3)
void attn_kernel(const short* __restrict__ Qb, const short* __restrict__ Kb,
                 const short* __restrict__ Vt, const float* __restrict__ gt,
                 short* __restrict__ out, int S)
{
    const int bh = blockIdx.z * 8 + blockIdx.x;
    const int b = bh >> 2, h = bh & 3;
    const int q0 = blockIdx.y << 4;
    const int tid = threadIdx.x;
    const int wave = tid >> 6, lane = tid & 63;
    const int l16 = lane & 15, quad = lane >> 4;

    __shared__ __align__(16) float Lw[16][4];
    __shared__ __align__(16) short Pb[16][PBS];   // [q][pos], 512 permuted keys

    const int kb0 = wave * 128;
    const short* Kbh = Kb + (size_t)bh * SPAD * 64;
    const short* Vbh = Vt + (size_t)bh * 64 * SPAD;

    // ---- prefetch Q + all 16 K-frags ----
    const size_t qrow = ((size_t)bh * SPAD + q0 + l16) * 64;
    const short8 aq0 = *(const short8*)(Qb + qrow + quad * 8);
    const short8 aq1 = *(const short8*)(Qb + qrow + 32 + quad * 8);

    short8 kf[16];
    #pragma unroll
    for (int c = 0; c < 4; ++c) {
        const size_t kr = (size_t)(kb0 + c * 32 + l16) * 64 + quad * 8;
        kf[4 * c + 0] = *(const short8*)(Kbh + kr);
        kf[4 * c + 1] = *(const short8*)(Kbh + kr + 32);
        kf[4 * c + 2] = *(const short8*)(Kbh + kr + 16 * 64);
        kf[4 * c + 3] = *(const short8*)(Kbh + kr + 16 * 64 + 32);
    }
    #pragma unroll
    for (int i = 0; i < 16; ++i) KEEP(kf[i]);

    // ---- phase 1: QK^T scores, 8 independent accumulator chains ----
    f32x4 sc[8];
    #pragma unroll
    for (int c = 0; c < 4; ++c) {
        const int kbase = kb0 + c * 32;
        f32x4 s0 = (f32x4){0.f, 0.f, 0.f, 0.f}, s1 = (f32x4){0.f, 0.f, 0.f, 0.f};
        s0 = __builtin_amdgcn_mfma_f32_16x16x32_bf16(aq0, kf[4 * c + 0], s0, 0, 0, 0);
        s0 = __builtin_amdgcn_mfma_f32_16x16x32_bf16(aq1, kf[4 * c + 1], s0, 0, 0, 0);
        s1 = __builtin_amdgcn_mfma_f32_16x16x32_bf16(aq0, kf[4 * c + 2], s1, 0, 0, 0);
        s1 = __builtin_amdgcn_mfma_f32_16x16x32_bf16(aq1, kf[4 * c + 3], s1, 0, 0, 0);
        if (kbase + 32 > S) {
            const bool v0 = (kbase + l16) < S, v1 = (kbase + 16 + l16) < S;
            #pragma unroll
            for (int r = 0; r < 4; ++r) {
                s0[r] = v0 ? s0[r] : -INFINITY;
                s1[r] = v1 ? s1[r] : -INFINITY;
            }
        }
        sc[2 * c] = s0; sc[2 * c + 1] = s1;
    }

    // ---- gate prefetch (consumed in phase 3; overlaps exp/reduce) ----
    f32x2 gpre[16];
    const float* gbase = gt + (((size_t)h) << 18) +
                         (((size_t)(q0 + quad * 4)) << 9) + kb0 + 2 * l16;
    #pragma unroll
    for (int r = 0; r < 4; ++r)
        #pragma unroll
        for (int c = 0; c < 4; ++c)
            gpre[r * 4 + c] = *(const f32x2*)(gbase + ((size_t)r << 9) + c * 32);
    #pragma unroll
    for (int i = 0; i < 16; ++i) KEEP(gpre[i]);

    // ---- V batch-0 prefetch (no P dependence; overlaps exp + pack + barrier) ----
    const int dsl = wave * 16;
    const short* Vrow = Vbh + (size_t)(dsl + l16) * SPAD + quad * 8;
    short8 vf0[8];
    #pragma unroll
    for (int j = 0; j < 8; ++j) vf0[j] = *(const short8*)(Vrow + j * 32);
    #pragma unroll
    for (int j = 0; j < 8; ++j) KEEP(vf0[j]);

    // ---- phase 2: exp2 + row sums ----
    float ls[4] = {0.f, 0.f, 0.f, 0.f};
    #pragma unroll
    for (int j = 0; j < 8; ++j) {
        #pragma unroll
        for (int r = 0; r < 4; ++r) {
            const float e = exp2_fast(sc[j][r]);
            sc[j][r] = e;
            ls[r] += e;
        }
    }
    #pragma unroll
    for (int r = 0; r < 4; ++r) {
        ls[r] += __shfl_xor(ls[r], 1, 64);
        ls[r] += __shfl_xor(ls[r], 2, 64);
        ls[r] += __shfl_xor(ls[r], 4, 64);
        ls[r] += __shfl_xor(ls[r], 8, 64);
    }
    if (l16 == 0) {
        #pragma unroll
        for (int r = 0; r < 4; ++r) Lw[quad * 4 + r][wave] = ls[r];
    }

    // ---- phase 3: table gate + cvt_pk -> packed b32 P writes (permuted layout) ----
    #pragma unroll
    for (int c = 0; c < 4; ++c) {
        #pragma unroll
        for (int r = 0; r < 4; ++r) {
            const f32x2 g = gpre[r * 4 + c];
            const float p0 = sc[2 * c][r] * g.x;
            const float p1 = sc[2 * c + 1][r] * g.y;
            unsigned int pk;
            asm("v_cvt_pk_bf16_f32 %0, %1, %2" : "=v"(pk) : "v"(p0), "v"(p1));
            *(unsigned int*)(&Pb[quad * 4 + r][kb0 + c * 32 + 2 * l16]) = pk;
        }
    }
    __syncthreads();

    // ---- phase 4: PV; batch 0 uses prefetched V, batch 1 loads overlap batch-0 MFMAs ----
    const short* Prow = &Pb[l16][quad * 8];
    f32x4 O0 = (f32x4){0.f, 0.f, 0.f, 0.f}, O1 = (f32x4){0.f, 0.f, 0.f, 0.f};
    short8 vf1[8];
    #pragma unroll
    for (int j = 0; j < 8; ++j) vf1[j] = *(const short8*)(Vrow + (8 + j) * 32);
    #pragma unroll
    for (int j = 0; j < 8; j += 2) {
        const short8 ap0 = *(const short8*)(Prow + j * 32);
        const short8 ap1 = *(const short8*)(Prow + (j + 1) * 32);
        O0 = __builtin_amdgcn_mfma_f32_16x16x32_bf16(ap0, vf0[j], O0, 0, 0, 0);
        O1 = __builtin_amdgcn_mfma_f32_16x16x32_bf16(ap1, vf0[j + 1], O1, 0, 0, 0);
    }
    #pragma unroll
    for (int j = 0; j < 8; j += 2) {
        const short8 ap0 = *(const short8*)(Prow + (8 + j) * 32);
        const short8 ap1 = *(const short8*)(Prow + (9 + j) * 32);
        O0 = __builtin_amdgcn_mfma_f32_16x16x32_bf16(ap0, vf1[j], O0, 0, 0, 0);
        O1 = __builtin_amdgcn_mfma_f32_16x16x32_bf16(ap1, vf1[j + 1], O1, 0, 0, 0);
    }
    const f32x4 O = O0 + O1;

    // ---- epilogue: divide by global l, write bf16 ----
    #pragma unroll
    for (int r = 0; r < 4; ++r) {
        const int q = quad * 4 + r;
        const int s = q0 + q;
        if (s < S) {
            const f32x4 lv = *(const f32x4*)Lw[q];
            const float lq = (lv[0] + lv[1]) + (lv[2] + lv[3]);
            out[((size_t)b * S + s) * D + h * 64 + dsl + l16] =
                f2bf(O[r] * __builtin_amdgcn_rcpf(lq));
        }
    }
}

extern "C" void kernel_launch(void* const* d_in, const int* in_sizes, int n_in,
                              void* d_out, int out_size, void* d_ws, size_t ws_size,
                              hipStream_t stream)
{
    const float* samples = (const float*)d_in[0];
    const float* Wq      = (const float*)d_in[1];
    const float* Wk      = (const float*)d_in[2];
    const float* Wv      = (const float*)d_in[3];
    const float* attn_w  = (const float*)d_in[4];
    const float* fc_w    = (const float*)d_in[5];
    const float* fc_b    = (const float*)d_in[6];
    const float* mha_g   = (const float*)d_in[7];
    const float* mha_b   = (const float*)d_in[8];
    const float* w1      = (const float*)d_in[9];
    const float* b1      = (const float*)d_in[10];
    const float* w2      = (const float*)d_in[11];
    const float* b2      = (const float*)d_in[12];
    const float* dg      = (const float*)d_in[13];
    const float* db      = (const float*)d_in[14];
    const float* ow      = (const float*)d_in[15];
    const float* ob      = (const float*)d_in[16];
    const float* og      = (const float*)d_in[17];
    const float* obeta   = (const float*)d_in[18];
    const int*   Kp      = (const int*)d_in[20];

    const int Bsz = 128;
    const int S = in_sizes[0] / (Bsz * D);   // 501
    const int rows = Bsz * S;                // 64128
    const size_t n_el = (size_t)rows * D;
    const size_t n_pad = (size_t)Bsz * H * SPAD * 64;

    float* x   = (float*)d_out;
    short* xb  = (short*)d_ws;               // bf16 activations [rows][D]
    short* aob = xb + n_el;                  // attn out bf16; aliased as Vb and later hb
    short* hb  = aob;
    short* Vb  = aob;                        // row-major V [B*H][S][64], exactly n_el shorts
    short* Qb  = aob + n_el;                 // [B*H][512][64]
    short* Kb  = Qb + n_pad;                 // [B*H][512][64]
    short* Vt  = Kb + n_pad;                 // [B*H][64][512] (key-permuted)
    short* wts = Vt + n_pad;
    float* gtab = (float*)(wts + (size_t)NMAT * 65536);   // [L][H][512][512] f32, 8.4 MB

    PackArgs pa;
    for (int l = 0; l < 2; ++l) {
        const size_t wo = (size_t)l * 65536;
        pa.src[l*6 + 0] = Wq + wo;   pa.scale[l*6 + 0] = 0.125f * LOG2E;  // temp + log2e fold
        pa.src[l*6 + 1] = Wk + wo;   pa.scale[l*6 + 1] = 1.f;
        pa.src[l*6 + 2] = Wv + wo;   pa.scale[l*6 + 2] = 1.f;
        pa.src[l*6 + 3] = fc_w + wo; pa.scale[l*6 + 3] = 1.f;
        pa.src[l*6 + 4] = w1 + wo;   pa.scale[l*6 + 4] = 1.f;
        pa.src[l*6 + 5] = w2 + wo;   pa.scale[l*6 + 5] = 1.f;
    }
    pa.src[12] = ow; pa.scale[12] = 1.f;
    pa.dst = wts;
    pack_kernel<<<dim3(256, NMAT), 256, 0, stream>>>(pa);

    gate_tab_kernel<<<dim3(1024, H, 2), 256, 0, stream>>>(attn_w, Kp, gtab, S);

    copy_cast_kernel<<<(int)((n_el / 4 + 255) / 256), 256, 0, stream>>>(samples, x, xb, (long)n_el);

    const int gblocks = rows / 64;           // 1002
    const int qt = (S + 15) / 16;            // 32
    for (int l = 0; l < 2; ++l) {
        short* wl = wts + (size_t)l * 6 * 65536;
        qkv_gemm_kernel<<<gblocks, 256, 0, stream>>>(xb, wl, Qb, Kb, Vb, S);
        vt_transpose_kernel<<<dim3(8, Bsz * H), 256, 0, stream>>>(Vb, Vt, S);
        attn_kernel<<<dim3(8, qt, Bsz * H / 8), 256, 0, stream>>>(Qb, Kb, Vt,
                                              gtab + ((size_t)l << 20), aob, S);
        gemm_res_ln_kernel<<<gblocks, 256, 0, stream>>>(aob, wl + 3 * 65536,
                                              fc_b + (size_t)l * D, x,
                                              mha_g + (size_t)l * D, mha_b + (size_t)l * D,
                                              x, xb);
        gemm_relu_kernel<<<gblocks, 256, 0, stream>>>(xb, wl + 4 * 65536,
                                              b1 + (size_t)l * D, hb);
        gemm_res_ln_kernel<<<gblocks, 256, 0, stream>>>(hb, wl + 5 * 65536,
                                              b2 + (size_t)l * D, x,
                                              dg + (size_t)l * D, db + (size_t)l * D,
                                              x, xb);
    }
    gemm_res_ln_kernel<<<gblocks, 256, 0, stream>>>(xb, wts + 12 * 65536,
                                              ob, samples, og, obeta, x, xb);
}

// Round 4
// 1169.989 us; speedup vs baseline: 1.4308x; 1.1411x over previous
//
#include <hip/hip_runtime.h>
#include <cstdint>
#include <cstddef>
#include <cmath>

#define D 256
#define H 4
#define LN_EPS 1e-5f
#define SPAD 512
#define NMAT 13
#define PBS 520   // Pb row stride in shorts: 1040 B = 65*16 (aligned), 260 words
#define LOG2E 1.44269504088896340736f

typedef __attribute__((ext_vector_type(8))) short short8;
typedef __attribute__((ext_vector_type(4))) short short4v;
typedef __attribute__((ext_vector_type(4))) float f32x4;
typedef __attribute__((ext_vector_type(2))) float f32x2;
typedef __attribute__((ext_vector_type(4))) int i32x4;

static __device__ __forceinline__ short f2bf(float f) {
    union { float f; unsigned u; } a; a.f = f;
    unsigned r = a.u + 0x7fffu + ((a.u >> 16) & 1u);
    return (short)(r >> 16);
}

static __device__ __forceinline__ float exp2_fast(float x) {
#if __has_builtin(__builtin_amdgcn_exp2f)
    return __builtin_amdgcn_exp2f(x);
#else
    float r; asm("v_exp_f32 %0, %1" : "=v"(r) : "v"(x)); return r;
#endif
}

// exact int divide by small runtime divisor via float reciprocal + correction
static __device__ __forceinline__ int idivf(int x, int Kc, float rKc) {
    int q = (int)((float)x * rKc);
    q -= (q * Kc > x) ? 1 : 0;
    q += ((q + 1) * Kc <= x) ? 1 : 0;
    return q;
}

// ---------- pack fp32 W[k][n] -> bf16 fragment-ordered B ----------
struct PackArgs { const float* src[NMAT]; float scale[NMAT]; short* dst; };

__global__ __launch_bounds__(256)
void pack_kernel(PackArgs pa)
{
    const int mat = blockIdx.y;
    const int el = blockIdx.x * 256 + threadIdx.x;
    const int n = el & 255, k = el >> 8;
    const int nt = n >> 4, l16 = n & 15;
    const int kc = k >> 5, qd = (k >> 3) & 3, j = k & 7;
    const size_t didx = (((size_t)(kc * 16 + nt) * 64) + qd * 16 + l16) * 8 + j;
    pa.dst[(size_t)mat * 65536 + didx] =
        f2bf(pa.src[mat][(size_t)k * 256 + n] * pa.scale[mat]);
}

// ---------- gate CLASS table: gc[l][h][cls][pos], cls = q/Kc (0..19) or 20 (query row) ----------
// pos is the PERMUTED key index: within each 32-block, key = 16*(pos&1) + ((pos>>1)&15).
// Diagonal (key==q -> g0) is NOT baked; fixed in attn with a cndmask.
__global__ __launch_bounds__(256)
void gate_cls_kernel(const float* __restrict__ aw, const int* __restrict__ Kp,
                     float* __restrict__ gc, int S)
{
    const int idx = blockIdx.x * 256 + threadIdx.x;   // cls*512 + pos, 21*512 = 10752
    const int h = blockIdx.y, l = blockIdx.z;
    const int cls = idx >> 9, pos = idx & 511;
    const int key = (pos & ~31) | ((pos & 1) << 4) | ((pos >> 1) & 15);
    const int NK = S - 1;
    const int Kc = Kp[0];
    int cat;
    if (cls < 20) cat = (key == NK) ? 3 : ((key < NK && key / Kc == cls) ? 1 : 2);
    else          cat = (key == NK) ? 5 : 4;
    gc[((size_t)(l * H + h) * 21 + cls) * 512 + pos] = tanhf(aw[(l * H + h) * 6 + cat]);
}

// ---------- fused fp32 copy + bf16 cast ----------
__global__ __launch_bounds__(256)
void copy_cast_kernel(const float* __restrict__ x, float* __restrict__ xc,
                      short* __restrict__ xb, long n)
{
    const long i = ((long)blockIdx.x * 256 + threadIdx.x) * 4;
    if (i >= n) return;
    const f32x4 v = *(const f32x4*)(x + i);
    *(f32x4*)(xc + i) = v;
    short4v o;
    o.x = f2bf(v.x); o.y = f2bf(v.y); o.z = f2bf(v.z); o.w = f2bf(v.w);
    *(short4v*)(xb + i) = o;
}

// ---------- MFMA mainloop with LDS-staged B: 16 rows x 256 cols per wave, K=256 ----------
// B is fragment-ordered => each 32-K chunk is a LINEAR 16 KB block. Double-buffered
// LDS staging: B read from L2 once per BLOCK (was once per WAVE = 4x), and per-thread
// global load count drops 128 -> 32. MFMA order identical to the global version.
static __device__ __forceinline__ void gemm_tile_lds(const short* __restrict__ A,
                                                     const short* __restrict__ Bt,
                                                     short (&Bs)[2][8192],
                                                     int rowA, int tid, int lane, int quad,
                                                     f32x4 (&acc)[16])
{
    const short* Ar = A + (size_t)rowA * D + quad * 8;
    #pragma unroll
    for (int nt = 0; nt < 16; ++nt) acc[nt] = (f32x4){0.f, 0.f, 0.f, 0.f};
    {
        const short8* src = (const short8*)Bt + tid;
        short8* dst = (short8*)Bs[0] + tid;
        #pragma unroll
        for (int i = 0; i < 4; ++i) dst[i * 256] = src[i * 256];
    }
    __syncthreads();
    #pragma unroll
    for (int kc = 0; kc < 8; ++kc) {
        short8 stg0, stg1, stg2, stg3;
        if (kc < 7) {
            const short8* src = (const short8*)(Bt + (size_t)(kc + 1) * 8192) + tid;
            stg0 = src[0]; stg1 = src[256]; stg2 = src[512]; stg3 = src[768];
        }
        const short8 af = *(const short8*)(Ar + kc * 32);
        const short* Bl = Bs[kc & 1] + lane * 8;
        #pragma unroll
        for (int nt = 0; nt < 16; ++nt) {
            const short8 bf = *(const short8*)(Bl + nt * 512);
            acc[nt] = __builtin_amdgcn_mfma_f32_16x16x32_bf16(af, bf, acc[nt], 0, 0, 0);
        }
        if (kc < 7) {
            short8* dst = (short8*)Bs[(kc + 1) & 1] + tid;
            dst[0] = stg0; dst[256] = stg1; dst[512] = stg2; dst[768] = stg3;
        }
        __syncthreads();
    }
}

// ---------- GEMM + bias + residual + LayerNorm, writes fp32 + bf16 ----------
__global__ __launch_bounds__(256)
void gemm_res_ln_kernel(const short* __restrict__ A, const short* __restrict__ Bt,
                        const float* __restrict__ bias, const float* __restrict__ resid,
                        const float* __restrict__ gam, const float* __restrict__ bet,
                        float* __restrict__ xout, short* __restrict__ xbout)
{
    const int tid = threadIdx.x, wave = tid >> 6, lane = tid & 63;
    const int l16 = lane & 15, quad = lane >> 4;
    const int row0 = blockIdx.x * 64 + wave * 16;
    __shared__ __align__(16) short Bs[2][8192];
    f32x4 acc[16];
    gemm_tile_lds(A, Bt, Bs, row0 + l16, tid, lane, quad, acc);

    #pragma unroll
    for (int nt = 0; nt < 16; ++nt) {
        const int col = nt * 16 + l16;
        const float bl = bias[col];
        #pragma unroll
        for (int r = 0; r < 4; ++r)
            acc[nt][r] += bl + resid[(size_t)(row0 + quad * 4 + r) * D + col];
    }
    float mu[4], rstd[4];
    #pragma unroll
    for (int r = 0; r < 4; ++r) {
        float s = 0.f;
        #pragma unroll
        for (int nt = 0; nt < 16; ++nt) s += acc[nt][r];
        s += __shfl_xor(s, 1, 64); s += __shfl_xor(s, 2, 64);
        s += __shfl_xor(s, 4, 64); s += __shfl_xor(s, 8, 64);
        mu[r] = s * (1.f / D);
        float q = 0.f;
        #pragma unroll
        for (int nt = 0; nt < 16; ++nt) { const float d = acc[nt][r] - mu[r]; q = fmaf(d, d, q); }
        q += __shfl_xor(q, 1, 64); q += __shfl_xor(q, 2, 64);
        q += __shfl_xor(q, 4, 64); q += __shfl_xor(q, 8, 64);
        rstd[r] = rsqrtf(q * (1.f / D) + LN_EPS);
    }
    #pragma unroll
    for (int nt = 0; nt < 16; ++nt) {
        const int col = nt * 16 + l16;
        const float g = gam[col], be = bet[col];
        #pragma unroll
        for (int r = 0; r < 4; ++r) {
            const size_t idx = (size_t)(row0 + quad * 4 + r) * D + col;
            const float o = (acc[nt][r] - mu[r]) * rstd[r] * g + be;
            xout[idx] = o;
            xbout[idx] = f2bf(o);
        }
    }
}

// ---------- GEMM + bias + relu -> bf16 ----------
__global__ __launch_bounds__(256)
void gemm_relu_kernel(const short* __restrict__ A, const short* __restrict__ Bt,
                      const float* __restrict__ bias, short* __restrict__ hb)
{
    const int tid = threadIdx.x, wave = tid >> 6, lane = tid & 63;
    const int l16 = lane & 15, quad = lane >> 4;
    const int row0 = blockIdx.x * 64 + wave * 16;
    __shared__ __align__(16) short Bs[2][8192];
    f32x4 acc[16];
    gemm_tile_lds(A, Bt, Bs, row0 + l16, tid, lane, quad, acc);
    #pragma unroll
    for (int nt = 0; nt < 16; ++nt) {
        const int col = nt * 16 + l16;
        const float bl = bias[col];
        #pragma unroll
        for (int r = 0; r < 4; ++r)
            hb[(size_t)(row0 + quad * 4 + r) * D + col] = f2bf(fmaxf(acc[nt][r] + bl, 0.f));
    }
}

// ---------- QKV: three GEMMs. Q,K padded layouts; V ROW-MAJOR (coalesced) ----------
__global__ __launch_bounds__(256)
void qkv_gemm_kernel(const short* __restrict__ A, const short* __restrict__ Wt,
                     short* __restrict__ Qb, short* __restrict__ Kb,
                     short* __restrict__ Vb, int S)
{
    const int tid = threadIdx.x, wave = tid >> 6, lane = tid & 63;
    const int l16 = lane & 15, quad = lane >> 4;
    const int row0 = blockIdx.x * 64 + wave * 16;
    __shared__ __align__(16) short Bs[2][8192];
    int bb[4], ss[4];
    #pragma unroll
    for (int r = 0; r < 4; ++r) {
        const int row = row0 + quad * 4 + r;
        bb[r] = row / S; ss[r] = row - bb[r] * S;
    }
    #pragma unroll 1
    for (int m = 0; m < 3; ++m) {
        f32x4 acc[16];
        gemm_tile_lds(A, Wt + (size_t)m * 65536, Bs, row0 + l16, tid, lane, quad, acc);
        #pragma unroll
        for (int nt = 0; nt < 16; ++nt) {
            const int col = nt * 16 + l16, h = col >> 6, dim = col & 63;
            #pragma unroll
            for (int r = 0; r < 4; ++r) {
                const int bh = bb[r] * H + h;
                const short v = f2bf(acc[nt][r]);
                if (m == 0)      Qb[((size_t)bh * SPAD + ss[r]) * 64 + dim] = v;
                else if (m == 1) Kb[((size_t)bh * SPAD + ss[r]) * 64 + dim] = v;
                else             Vb[((size_t)bh * S + ss[r]) * 64 + dim] = v;   // row-major, unpadded
            }
        }
    }
}

// ---------- V transpose: [bh][s][64] -> Vt[bh][64][pos] (permuted, padded, zero tail) ----------
__global__ __launch_bounds__(256)
void vt_transpose_kernel(const short* __restrict__ Vb, short* __restrict__ Vt, int S)
{
    const int bh = blockIdx.y;
    const int s0 = blockIdx.x * 64;
    const int t = threadIdx.x;
    __shared__ short T[64][72];
    {
        const int r = t >> 2, c = (t & 3) * 16;
        const int s = s0 + r;
        short8 v0 = (short8){0,0,0,0,0,0,0,0}, v1 = (short8){0,0,0,0,0,0,0,0};
        if (s < S) {
            const short* src = Vb + ((size_t)bh * S + s) * 64 + c;
            v0 = *(const short8*)src;
            v1 = *(const short8*)(src + 8);
        }
        *(short8*)&T[r][c] = v0;
        *(short8*)&T[r][c + 8] = v1;
    }
    __syncthreads();
    {
        const int dim = t >> 2, g = t & 3;
        int w[8];
        #pragma unroll
        for (int j = 0; j < 8; ++j) {
            const int d = g * 8 + j;                       // dword index 0..31 in this 64-span
            const int k0 = ((d >> 4) << 5) | (d & 15);     // key row in tile (pair partner +16)
            const unsigned lo = (unsigned short)T[k0][dim];
            const unsigned hi = (unsigned short)T[k0 + 16][dim];
            w[j] = (int)(lo | (hi << 16));
        }
        int* dst = (int*)(Vt + ((size_t)bh * 64 + dim) * SPAD + s0) + g * 8;
        *(i32x4*)dst = (i32x4){w[0], w[1], w[2], w[3]};
        *(i32x4*)(dst + 4) = (i32x4){w[4], w[5], w[6], w[7]};
    }
}

// ---------------- MFMA attention: 4 q-tiles per block, class-table gates ----------------
// Wq prescaled by log2e/temperature so exp is a single v_exp_f32 (2^x domain).
// grid = dim3(8, 8, B*H/8); each block loops 4 q-tiles of one bh. K/V/gate
// addresses are loop-invariant => iters 1-3 hit L1/L2 (cuts L3 traffic ~3x).
// Gates come from the tiny 344 KB class table (L2-hot); diagonal fixed via cndmask.
// Pb/Lw double-buffered => one barrier per iter.
__global__ __launch_bounds__(256, 3)
void attn_kernel(const short* __restrict__ Qb, const short* __restrict__ Kb,
                 const short* __restrict__ Vt, const float* __restrict__ gc,
                 const float* __restrict__ awl, const int* __restrict__ Kp,
                 short* __restrict__ out, int S)
{
    const int bh = blockIdx.z * 8 + blockIdx.x;
    const int b = bh >> 2, h = bh & 3;
    const int tid = threadIdx.x;
    const int wave = tid >> 6, lane = tid & 63;
    const int l16 = lane & 15, quad = lane >> 4;
    const int NK = S - 1;
    const int Kc = Kp[0];
    const float rKc = 1.0f / (float)Kc;
    const float g0 = tanhf(awl[h * 6]);

    __shared__ __align__(16) float Lw[2][16][4];
    __shared__ __align__(16) short Pb[2][16][PBS];

    const int kb0 = wave * 128;
    const short* Kbh = Kb + (size_t)bh * SPAD * 64;
    const short* Vbh = Vt + (size_t)bh * 64 * SPAD;
    const float* gch = gc + (size_t)h * (21 * 512);
    const int dsl = wave * 16;
    const short* Vrow = Vbh + (size_t)(dsl + l16) * SPAD + quad * 8;

    #pragma unroll 1
    for (int it = 0; it < 4; ++it) {
        const int q0 = (blockIdx.y * 4 + it) << 4;
        const int bsel = it & 1;

        // ---- Q + K frags; QK^T scores (K addresses loop-invariant -> L1/L2 hit) ----
        const size_t qrow = ((size_t)bh * SPAD + q0 + l16) * 64;
        const short8 aq0 = *(const short8*)(Qb + qrow + quad * 8);
        const short8 aq1 = *(const short8*)(Qb + qrow + 32 + quad * 8);

        f32x4 sc[8];
        #pragma unroll
        for (int c = 0; c < 4; ++c) {
            const int kbase = kb0 + c * 32;
            const size_t kr = (size_t)(kbase + l16) * 64 + quad * 8;
            const short8 k00 = *(const short8*)(Kbh + kr);
            const short8 k01 = *(const short8*)(Kbh + kr + 32);
            const short8 k10 = *(const short8*)(Kbh + kr + 16 * 64);
            const short8 k11 = *(const short8*)(Kbh + kr + 16 * 64 + 32);
            f32x4 s0 = (f32x4){0.f, 0.f, 0.f, 0.f}, s1 = (f32x4){0.f, 0.f, 0.f, 0.f};
            s0 = __builtin_amdgcn_mfma_f32_16x16x32_bf16(aq0, k00, s0, 0, 0, 0);
            s0 = __builtin_amdgcn_mfma_f32_16x16x32_bf16(aq1, k01, s0, 0, 0, 0);
            s1 = __builtin_amdgcn_mfma_f32_16x16x32_bf16(aq0, k10, s1, 0, 0, 0);
            s1 = __builtin_amdgcn_mfma_f32_16x16x32_bf16(aq1, k11, s1, 0, 0, 0);
            if (kbase + 32 > S) {
                const bool v0 = (kbase + l16) < S, v1 = (kbase + 16 + l16) < S;
                #pragma unroll
                for (int r = 0; r < 4; ++r) {
                    s0[r] = v0 ? s0[r] : -INFINITY;
                    s1[r] = v1 ? s1[r] : -INFINITY;
                }
            }
            sc[2 * c] = s0; sc[2 * c + 1] = s1;
        }

        // ---- gate prefetch from class table (hot in L1/L2) ----
        int dq[4]; const float* gr[4];
        #pragma unroll
        for (int r = 0; r < 4; ++r) {
            const int q = q0 + quad * 4 + r;
            const bool qs = q < NK;
            const int cls = qs ? idivf(q, Kc, rKc) : 20;
            gr[r] = gch + (size_t)cls * 512 + kb0 + 2 * l16;
            dq[r] = qs ? q : -1;
        }
        f32x2 gpre[16];
        #pragma unroll
        for (int r = 0; r < 4; ++r)
            #pragma unroll
            for (int c = 0; c < 4; ++c)
                gpre[r * 4 + c] = *(const f32x2*)(gr[r] + c * 32);

        // ---- V batch-0 prefetch (overlaps exp + pack + barrier; L1-hot after iter 0) ----
        short8 vf0[8];
        #pragma unroll
        for (int j = 0; j < 8; ++j) vf0[j] = *(const short8*)(Vrow + j * 32);

        // ---- exp2 + row sums ----
        float ls[4] = {0.f, 0.f, 0.f, 0.f};
        #pragma unroll
        for (int j = 0; j < 8; ++j) {
            #pragma unroll
            for (int r = 0; r < 4; ++r) {
                const float e = exp2_fast(sc[j][r]);
                sc[j][r] = e;
                ls[r] += e;
            }
        }
        #pragma unroll
        for (int r = 0; r < 4; ++r) {
            ls[r] += __shfl_xor(ls[r], 1, 64);
            ls[r] += __shfl_xor(ls[r], 2, 64);
            ls[r] += __shfl_xor(ls[r], 4, 64);
            ls[r] += __shfl_xor(ls[r], 8, 64);
        }
        if (l16 == 0) {
            #pragma unroll
            for (int r = 0; r < 4; ++r) Lw[bsel][quad * 4 + r][wave] = ls[r];
        }

        // ---- gate (with diagonal cndmask fix) + cvt_pk -> packed b32 P writes ----
        #pragma unroll
        for (int c = 0; c < 4; ++c) {
            const int key0 = kb0 + c * 32 + l16, key1 = key0 + 16;
            #pragma unroll
            for (int r = 0; r < 4; ++r) {
                const f32x2 g = gpre[r * 4 + c];
                const float gx = (key0 == dq[r]) ? g0 : g.x;
                const float gy = (key1 == dq[r]) ? g0 : g.y;
                const float p0 = sc[2 * c][r] * gx;
                const float p1 = sc[2 * c + 1][r] * gy;
                unsigned int pk;
                asm("v_cvt_pk_bf16_f32 %0, %1, %2" : "=v"(pk) : "v"(p0), "v"(p1));
                *(unsigned int*)(&Pb[bsel][quad * 4 + r][kb0 + c * 32 + 2 * l16]) = pk;
            }
        }
        __syncthreads();

        // ---- PV for this wave's d-slice; V addresses loop-invariant ----
        const short* Prow = &Pb[bsel][l16][quad * 8];
        f32x4 O0 = (f32x4){0.f, 0.f, 0.f, 0.f}, O1 = (f32x4){0.f, 0.f, 0.f, 0.f};
        short8 vf1[8];
        #pragma unroll
        for (int j = 0; j < 8; ++j) vf1[j] = *(const short8*)(Vrow + (8 + j) * 32);
        #pragma unroll
        for (int j = 0; j < 8; j += 2) {
            const short8 ap0 = *(const short8*)(Prow + j * 32);
            const short8 ap1 = *(const short8*)(Prow + (j + 1) * 32);
            O0 = __builtin_amdgcn_mfma_f32_16x16x32_bf16(ap0, vf0[j], O0, 0, 0, 0);
            O1 = __builtin_amdgcn_mfma_f32_16x16x32_bf16(ap1, vf0[j + 1], O1, 0, 0, 0);
        }
        #pragma unroll
        for (int j = 0; j < 8; j += 2) {
            const short8 ap0 = *(const short8*)(Prow + (8 + j) * 32);
            const short8 ap1 = *(const short8*)(Prow + (9 + j) * 32);
            O0 = __builtin_amdgcn_mfma_f32_16x16x32_bf16(ap0, vf1[j], O0, 0, 0, 0);
            O1 = __builtin_amdgcn_mfma_f32_16x16x32_bf16(ap1, vf1[j + 1], O1, 0, 0, 0);
        }
        const f32x4 O = O0 + O1;

        // ---- epilogue: divide by global l, write bf16 ----
        #pragma unroll
        for (int r = 0; r < 4; ++r) {
            const int q = quad * 4 + r;
            const int s = q0 + q;
            if (s < S) {
                const f32x4 lv = *(const f32x4*)Lw[bsel][q];
                const float lq = (lv[0] + lv[1]) + (lv[2] + lv[3]);
                out[((size_t)b * S + s) * D + h * 64 + dsl + l16] =
                    f2bf(O[r] * __builtin_amdgcn_rcpf(lq));
            }
        }
    }
}

extern "C" void kernel_launch(void* const* d_in, const int* in_sizes, int n_in,
                              void* d_out, int out_size, void* d_ws, size_t ws_size,
                              hipStream_t stream)
{
    const float* samples = (const float*)d_in[0];
    const float* Wq      = (const float*)d_in[1];
    const float* Wk      = (const float*)d_in[2];
    const float* Wv      = (const float*)d_in[3];
    const float* attn_w  = (const float*)d_in[4];
    const float* fc_w    = (const float*)d_in[5];
    const float* fc_b    = (const float*)d_in[6];
    const float* mha_g   = (const float*)d_in[7];
    const float* mha_b   = (const float*)d_in[8];
    const float* w1      = (const float*)d_in[9];
    const float* b1      = (const float*)d_in[10];
    const float* w2      = (const float*)d_in[11];
    const float* b2      = (const float*)d_in[12];
    const float* dg      = (const float*)d_in[13];
    const float* db      = (const float*)d_in[14];
    const float* ow      = (const float*)d_in[15];
    const float* ob      = (const float*)d_in[16];
    const float* og      = (const float*)d_in[17];
    const float* obeta   = (const float*)d_in[18];
    const int*   Kp      = (const int*)d_in[20];

    const int Bsz = 128;
    const int S = in_sizes[0] / (Bsz * D);   // 501
    const int rows = Bsz * S;                // 64128
    const size_t n_el = (size_t)rows * D;
    const size_t n_pad = (size_t)Bsz * H * SPAD * 64;

    float* x   = (float*)d_out;
    short* xb  = (short*)d_ws;               // bf16 activations [rows][D]
    short* aob = xb + n_el;                  // attn out bf16; aliased as Vb and later hb
    short* hb  = aob;
    short* Vb  = aob;                        // row-major V [B*H][S][64], exactly n_el shorts
    short* Qb  = aob + n_el;                 // [B*H][512][64]
    short* Kb  = Qb + n_pad;                 // [B*H][512][64]
    short* Vt  = Kb + n_pad;                 // [B*H][64][512] (key-permuted)
    short* wts = Vt + n_pad;
    float* gcls = (float*)(wts + (size_t)NMAT * 65536);   // [L][H][21][512] f32, 344 KB

    PackArgs pa;
    for (int l = 0; l < 2; ++l) {
        const size_t wo = (size_t)l * 65536;
        pa.src[l*6 + 0] = Wq + wo;   pa.scale[l*6 + 0] = 0.125f * LOG2E;  // temp + log2e fold
        pa.src[l*6 + 1] = Wk + wo;   pa.scale[l*6 + 1] = 1.f;
        pa.src[l*6 + 2] = Wv + wo;   pa.scale[l*6 + 2] = 1.f;
        pa.src[l*6 + 3] = fc_w + wo; pa.scale[l*6 + 3] = 1.f;
        pa.src[l*6 + 4] = w1 + wo;   pa.scale[l*6 + 4] = 1.f;
        pa.src[l*6 + 5] = w2 + wo;   pa.scale[l*6 + 5] = 1.f;
    }
    pa.src[12] = ow; pa.scale[12] = 1.f;
    pa.dst = wts;
    pack_kernel<<<dim3(256, NMAT), 256, 0, stream>>>(pa);

    gate_cls_kernel<<<dim3(42, H, 2), 256, 0, stream>>>(attn_w, Kp, gcls, S);

    copy_cast_kernel<<<(int)((n_el / 4 + 255) / 256), 256, 0, stream>>>(samples, x, xb, (long)n_el);

    const int gblocks = rows / 64;           // 1002
    for (int l = 0; l < 2; ++l) {
        short* wl = wts + (size_t)l * 6 * 65536;
        qkv_gemm_kernel<<<gblocks, 256, 0, stream>>>(xb, wl, Qb, Kb, Vb, S);
        vt_transpose_kernel<<<dim3(8, Bsz * H), 256, 0, stream>>>(Vb, Vt, S);
        attn_kernel<<<dim3(8, 8, Bsz * H / 8), 256, 0, stream>>>(Qb, Kb, Vt,
                                              gcls + (size_t)l * H * 21 * 512,
                                              attn_w + (size_t)l * H * 6, Kp, aob, S);
        gemm_res_ln_kernel<<<gblocks, 256, 0, stream>>>(aob, wl + 3 * 65536,
                                              fc_b + (size_t)l * D, x,
                                              mha_g + (size_t)l * D, mha_b + (size_t)l * D,
                                              x, xb);
        gemm_relu_kernel<<<gblocks, 256, 0, stream>>>(xb, wl + 4 * 65536,
                                              b1 + (size_t)l * D, hb);
        gemm_res_ln_kernel<<<gblocks, 256, 0, stream>>>(hb, wl + 5 * 65536,
                                              b2 + (size_t)l * D, x,
                                              dg + (size_t)l * D, db + (size_t)l * D,
                                              x, xb);
    }
    gemm_res_ln_kernel<<<gblocks, 256, 0, stream>>>(xb, wts + 12 * 65536,
                                              ob, samples, og, obeta, x, xb);
}

// Round 6
// 849.998 us; speedup vs baseline: 1.9695x; 1.3765x over previous
//
#include <hip/hip_runtime.h>
#include <cstdint>
#include <cstddef>
#include <cmath>

#define D 256
#define H 4
#define LN_EPS 1e-5f
#define SPAD 512
#define NMAT 13
#define PBS 520   // Pb row stride in shorts: 1040 B = 65*16 (aligned), 260 words
#define LOG2E 1.44269504088896340736f

typedef __attribute__((ext_vector_type(8))) short short8;
typedef __attribute__((ext_vector_type(4))) short short4v;
typedef __attribute__((ext_vector_type(4))) float f32x4;
typedef __attribute__((ext_vector_type(2))) float f32x2;
typedef __attribute__((ext_vector_type(4))) int i32x4;

static __device__ __forceinline__ short f2bf(float f) {
    union { float f; unsigned u; } a; a.f = f;
    unsigned r = a.u + 0x7fffu + ((a.u >> 16) & 1u);
    return (short)(r >> 16);
}

static __device__ __forceinline__ float exp2_fast(float x) {
#if __has_builtin(__builtin_amdgcn_exp2f)
    return __builtin_amdgcn_exp2f(x);
#else
    float r; asm("v_exp_f32 %0, %1" : "=v"(r) : "v"(x)); return r;
#endif
}

// exact int divide by small runtime divisor via float reciprocal + correction
static __device__ __forceinline__ int idivf(int x, int Kc, float rKc) {
    int q = (int)((float)x * rKc);
    q -= (q * Kc > x) ? 1 : 0;
    q += ((q + 1) * Kc <= x) ? 1 : 0;
    return q;
}

// ---------- pack fp32 W[k][n] -> bf16 fragment-ordered B ----------
struct PackArgs { const float* src[NMAT]; float scale[NMAT]; short* dst; };

__global__ __launch_bounds__(256)
void pack_kernel(PackArgs pa)
{
    const int mat = blockIdx.y;
    const int el = blockIdx.x * 256 + threadIdx.x;
    const int n = el & 255, k = el >> 8;
    const int nt = n >> 4, l16 = n & 15;
    const int kc = k >> 5, qd = (k >> 3) & 3, j = k & 7;
    const size_t didx = (((size_t)(kc * 16 + nt) * 64) + qd * 16 + l16) * 8 + j;
    pa.dst[(size_t)mat * 65536 + didx] =
        f2bf(pa.src[mat][(size_t)k * 256 + n] * pa.scale[mat]);
}

// ---------- gate CLASS table: gc[l][h][cls][pos], cls = q/Kc (0..19) or 20 (query row) ----------
// pos is the PERMUTED key index: within each 32-block, key = 16*(pos&1) + ((pos>>1)&15).
// Diagonal (key==q -> g0) is NOT baked; fixed in attn with a cndmask.
__global__ __launch_bounds__(256)
void gate_cls_kernel(const float* __restrict__ aw, const int* __restrict__ Kp,
                     float* __restrict__ gc, int S)
{
    const int idx = blockIdx.x * 256 + threadIdx.x;   // cls*512 + pos, 21*512 = 10752
    const int h = blockIdx.y, l = blockIdx.z;
    const int cls = idx >> 9, pos = idx & 511;
    const int key = (pos & ~31) | ((pos & 1) << 4) | ((pos >> 1) & 15);
    const int NK = S - 1;
    const int Kc = Kp[0];
    int cat;
    if (cls < 20) cat = (key == NK) ? 3 : ((key < NK && key / Kc == cls) ? 1 : 2);
    else          cat = (key == NK) ? 5 : 4;
    gc[((size_t)(l * H + h) * 21 + cls) * 512 + pos] = tanhf(aw[(l * H + h) * 6 + cat]);
}

// ---------- fused fp32 copy + bf16 cast ----------
__global__ __launch_bounds__(256)
void copy_cast_kernel(const float* __restrict__ x, float* __restrict__ xc,
                      short* __restrict__ xb, long n)
{
    const long i = ((long)blockIdx.x * 256 + threadIdx.x) * 4;
    if (i >= n) return;
    const f32x4 v = *(const f32x4*)(x + i);
    *(f32x4*)(xc + i) = v;
    short4v o;
    o.x = f2bf(v.x); o.y = f2bf(v.y); o.z = f2bf(v.z); o.w = f2bf(v.w);
    *(short4v*)(xb + i) = o;
}

// ---------- MFMA mainloop with LDS-staged B: 16 rows x 256 cols per wave, K=256 ----------
static __device__ __forceinline__ void gemm_tile_lds(const short* __restrict__ A,
                                                     const short* __restrict__ Bt,
                                                     short (&Bs)[2][8192],
                                                     int rowA, int tid, int lane, int quad,
                                                     f32x4 (&acc)[16])
{
    const short* Ar = A + (size_t)rowA * D + quad * 8;
    #pragma unroll
    for (int nt = 0; nt < 16; ++nt) acc[nt] = (f32x4){0.f, 0.f, 0.f, 0.f};
    {
        const short8* src = (const short8*)Bt + tid;
        short8* dst = (short8*)Bs[0] + tid;
        #pragma unroll
        for (int i = 0; i < 4; ++i) dst[i * 256] = src[i * 256];
    }
    __syncthreads();
    #pragma unroll
    for (int kc = 0; kc < 8; ++kc) {
        short8 stg0, stg1, stg2, stg3;
        if (kc < 7) {
            const short8* src = (const short8*)(Bt + (size_t)(kc + 1) * 8192) + tid;
            stg0 = src[0]; stg1 = src[256]; stg2 = src[512]; stg3 = src[768];
        }
        const short8 af = *(const short8*)(Ar + kc * 32);
        const short* Bl = Bs[kc & 1] + lane * 8;
        #pragma unroll
        for (int nt = 0; nt < 16; ++nt) {
            const short8 bf = *(const short8*)(Bl + nt * 512);
            acc[nt] = __builtin_amdgcn_mfma_f32_16x16x32_bf16(af, bf, acc[nt], 0, 0, 0);
        }
        if (kc < 7) {
            short8* dst = (short8*)Bs[(kc + 1) & 1] + tid;
            dst[0] = stg0; dst[256] = stg1; dst[512] = stg2; dst[768] = stg3;
        }
        __syncthreads();
    }
}

// ---------- GEMM + bias + residual + LayerNorm, writes fp32 + bf16 ----------
__global__ __launch_bounds__(256)
void gemm_res_ln_kernel(const short* __restrict__ A, const short* __restrict__ Bt,
                        const float* __restrict__ bias, const float* __restrict__ resid,
                        const float* __restrict__ gam, const float* __restrict__ bet,
                        float* __restrict__ xout, short* __restrict__ xbout)
{
    const int tid = threadIdx.x, wave = tid >> 6, lane = tid & 63;
    const int l16 = lane & 15, quad = lane >> 4;
    const int row0 = blockIdx.x * 64 + wave * 16;
    __shared__ __align__(16) short Bs[2][8192];
    f32x4 acc[16];
    gemm_tile_lds(A, Bt, Bs, row0 + l16, tid, lane, quad, acc);

    #pragma unroll
    for (int nt = 0; nt < 16; ++nt) {
        const int col = nt * 16 + l16;
        const float bl = bias[col];
        #pragma unroll
        for (int r = 0; r < 4; ++r)
            acc[nt][r] += bl + resid[(size_t)(row0 + quad * 4 + r) * D + col];
    }
    float mu[4], rstd[4];
    #pragma unroll
    for (int r = 0; r < 4; ++r) {
        float s = 0.f;
        #pragma unroll
        for (int nt = 0; nt < 16; ++nt) s += acc[nt][r];
        s += __shfl_xor(s, 1, 64); s += __shfl_xor(s, 2, 64);
        s += __shfl_xor(s, 4, 64); s += __shfl_xor(s, 8, 64);
        mu[r] = s * (1.f / D);
        float q = 0.f;
        #pragma unroll
        for (int nt = 0; nt < 16; ++nt) { const float d = acc[nt][r] - mu[r]; q = fmaf(d, d, q); }
        q += __shfl_xor(q, 1, 64); q += __shfl_xor(q, 2, 64);
        q += __shfl_xor(q, 4, 64); q += __shfl_xor(q, 8, 64);
        rstd[r] = rsqrtf(q * (1.f / D) + LN_EPS);
    }
    #pragma unroll
    for (int nt = 0; nt < 16; ++nt) {
        const int col = nt * 16 + l16;
        const float g = gam[col], be = bet[col];
        #pragma unroll
        for (int r = 0; r < 4; ++r) {
            const size_t idx = (size_t)(row0 + quad * 4 + r) * D + col;
            const float o = (acc[nt][r] - mu[r]) * rstd[r] * g + be;
            xout[idx] = o;
            xbout[idx] = f2bf(o);
        }
    }
}

// ---------- GEMM + bias + relu -> bf16 ----------
__global__ __launch_bounds__(256)
void gemm_relu_kernel(const short* __restrict__ A, const short* __restrict__ Bt,
                      const float* __restrict__ bias, short* __restrict__ hb)
{
    const int tid = threadIdx.x, wave = tid >> 6, lane = tid & 63;
    const int l16 = lane & 15, quad = lane >> 4;
    const int row0 = blockIdx.x * 64 + wave * 16;
    __shared__ __align__(16) short Bs[2][8192];
    f32x4 acc[16];
    gemm_tile_lds(A, Bt, Bs, row0 + l16, tid, lane, quad, acc);
    #pragma unroll
    for (int nt = 0; nt < 16; ++nt) {
        const int col = nt * 16 + l16;
        const float bl = bias[col];
        #pragma unroll
        for (int r = 0; r < 4; ++r)
            hb[(size_t)(row0 + quad * 4 + r) * D + col] = f2bf(fmaxf(acc[nt][r] + bl, 0.f));
    }
}

// ---------- QKV: three GEMMs. Q,K padded layouts; V ROW-MAJOR (coalesced) ----------
__global__ __launch_bounds__(256)
void qkv_gemm_kernel(const short* __restrict__ A, const short* __restrict__ Wt,
                     short* __restrict__ Qb, short* __restrict__ Kb,
                     short* __restrict__ Vb, int S)
{
    const int tid = threadIdx.x, wave = tid >> 6, lane = tid & 63;
    const int l16 = lane & 15, quad = lane >> 4;
    const int row0 = blockIdx.x * 64 + wave * 16;
    __shared__ __align__(16) short Bs[2][8192];
    int bb[4], ss[4];
    #pragma unroll
    for (int r = 0; r < 4; ++r) {
        const int row = row0 + quad * 4 + r;
        bb[r] = row / S; ss[r] = row - bb[r] * S;
    }
    #pragma unroll 1
    for (int m = 0; m < 3; ++m) {
        f32x4 acc[16];
        gemm_tile_lds(A, Wt + (size_t)m * 65536, Bs, row0 + l16, tid, lane, quad, acc);
        #pragma unroll
        for (int nt = 0; nt < 16; ++nt) {
            const int col = nt * 16 + l16, h = col >> 6, dim = col & 63;
            #pragma unroll
            for (int r = 0; r < 4; ++r) {
                const int bh = bb[r] * H + h;
                const short v = f2bf(acc[nt][r]);
                if (m == 0)      Qb[((size_t)bh * SPAD + ss[r]) * 64 + dim] = v;
                else if (m == 1) Kb[((size_t)bh * SPAD + ss[r]) * 64 + dim] = v;
                else             Vb[((size_t)bh * S + ss[r]) * 64 + dim] = v;   // row-major, unpadded
            }
        }
    }
}

// ---------- V transpose: [bh][s][64] -> Vt[bh][64][pos] (permuted, padded, zero tail) ----------
__global__ __launch_bounds__(256)
void vt_transpose_kernel(const short* __restrict__ Vb, short* __restrict__ Vt, int S)
{
    const int bh = blockIdx.y;
    const int s0 = blockIdx.x * 64;
    const int t = threadIdx.x;
    __shared__ short T[64][72];
    {
        const int r = t >> 2, c = (t & 3) * 16;
        const int s = s0 + r;
        short8 v0 = (short8){0,0,0,0,0,0,0,0}, v1 = (short8){0,0,0,0,0,0,0,0};
        if (s < S) {
            const short* src = Vb + ((size_t)bh * S + s) * 64 + c;
            v0 = *(const short8*)src;
            v1 = *(const short8*)(src + 8);
        }
        *(short8*)&T[r][c] = v0;
        *(short8*)&T[r][c + 8] = v1;
    }
    __syncthreads();
    {
        const int dim = t >> 2, g = t & 3;
        int w[8];
        #pragma unroll
        for (int j = 0; j < 8; ++j) {
            const int d = g * 8 + j;                       // dword index 0..31 in this 64-span
            const int k0 = ((d >> 4) << 5) | (d & 15);     // key row in tile (pair partner +16)
            const unsigned lo = (unsigned short)T[k0][dim];
            const unsigned hi = (unsigned short)T[k0 + 16][dim];
            w[j] = (int)(lo | (hi << 16));
        }
        int* dst = (int*)(Vt + ((size_t)bh * 64 + dim) * SPAD + s0) + g * 8;
        *(i32x4*)dst = (i32x4){w[0], w[1], w[2], w[3]};
        *(i32x4*)(dst + 4) = (i32x4){w[4], w[5], w[6], w[7]};
    }
}

// ---------------- MFMA attention: one block per (b,h), K+V resident in REGISTERS ----------------
// Wq prescaled by log2e/temperature so exp is a single v_exp_f32 (2^x domain).
// grid = 512 blocks (one per bh), 4 waves. Wave w owns keys [w*128,w*128+128) for QK
// and d-slice [w*16,w*16+16) for PV. kf[16] (wave's K-span, 64 VGPR) and vf[16]
// (wave's V-slice, 64 VGPR) are loaded ONCE, then the block loops all 32 q-tiles:
// per-iter global traffic is just Q (2 loads) + gates (8 loads, L2-hot). QK and PV
// read registers only; P transposes through double-buffered LDS (1 barrier/iter).
// __launch_bounds__(256,1): 1 wave/SIMD -> 512-VGPR budget, no spill at ~300 regs.
__global__ __launch_bounds__(256, 1)
void attn_kernel(const short* __restrict__ Qb, const short* __restrict__ Kb,
                 const short* __restrict__ Vt, const float* __restrict__ gc,
                 const float* __restrict__ awl, const int* __restrict__ Kp,
                 short* __restrict__ out, int S)
{
    const int bh = blockIdx.x;
    const int b = bh >> 2, h = bh & 3;
    const int tid = threadIdx.x;
    const int wave = tid >> 6, lane = tid & 63;
    const int l16 = lane & 15, quad = lane >> 4;
    const int NK = S - 1;
    const int Kc = Kp[0];
    const float rKc = 1.0f / (float)Kc;
    const float g0 = tanhf(awl[h * 6]);

    __shared__ __align__(16) float Lw[2][16][4];
    __shared__ __align__(16) short Pb[2][16][PBS];

    const int kb0 = wave * 128;
    const short* Kbh = Kb + (size_t)bh * SPAD * 64;
    const short* Vbh = Vt + (size_t)bh * 64 * SPAD;
    const float* gch = gc + (size_t)h * (21 * 512);
    const int dsl = wave * 16;
    const short* Vrow = Vbh + (size_t)(dsl + l16) * SPAD + quad * 8;

    // ---- hoisted: wave's 128-key K-span (64 VGPR) + 16-dim V-slice (64 VGPR) ----
    short8 kf[16];
    #pragma unroll
    for (int c = 0; c < 4; ++c) {
        const size_t kr = (size_t)(kb0 + c * 32 + l16) * 64 + quad * 8;
        kf[4 * c + 0] = *(const short8*)(Kbh + kr);
        kf[4 * c + 1] = *(const short8*)(Kbh + kr + 32);
        kf[4 * c + 2] = *(const short8*)(Kbh + kr + 16 * 64);
        kf[4 * c + 3] = *(const short8*)(Kbh + kr + 16 * 64 + 32);
    }
    short8 vf[16];
    #pragma unroll
    for (int ks = 0; ks < 16; ++ks) vf[ks] = *(const short8*)(Vrow + ks * 32);

    #pragma unroll 1
    for (int it = 0; it < 32; ++it) {
        const int q0 = it << 4;
        const int bsel = it & 1;

        // ---- Q frags for this q-tile ----
        const size_t qrow = ((size_t)bh * SPAD + q0 + l16) * 64;
        const short8 aq0 = *(const short8*)(Qb + qrow + quad * 8);
        const short8 aq1 = *(const short8*)(Qb + qrow + 32 + quad * 8);

        // ---- QK^T from registers ----
        f32x4 sc[8];
        #pragma unroll
        for (int c = 0; c < 4; ++c) {
            const int kbase = kb0 + c * 32;
            f32x4 s0 = (f32x4){0.f, 0.f, 0.f, 0.f}, s1 = (f32x4){0.f, 0.f, 0.f, 0.f};
            s0 = __builtin_amdgcn_mfma_f32_16x16x32_bf16(aq0, kf[4 * c + 0], s0, 0, 0, 0);
            s0 = __builtin_amdgcn_mfma_f32_16x16x32_bf16(aq1, kf[4 * c + 1], s0, 0, 0, 0);
            s1 = __builtin_amdgcn_mfma_f32_16x16x32_bf16(aq0, kf[4 * c + 2], s1, 0, 0, 0);
            s1 = __builtin_amdgcn_mfma_f32_16x16x32_bf16(aq1, kf[4 * c + 3], s1, 0, 0, 0);
            if (kbase + 32 > S) {
                const bool v0 = (kbase + l16) < S, v1 = (kbase + 16 + l16) < S;
                #pragma unroll
                for (int r = 0; r < 4; ++r) {
                    s0[r] = v0 ? s0[r] : -INFINITY;
                    s1[r] = v1 ? s1[r] : -INFINITY;
                }
            }
            sc[2 * c] = s0; sc[2 * c + 1] = s1;
        }

        // ---- gate prefetch from class table (L2-hot) ----
        int dq[4]; const float* gr[4];
        #pragma unroll
        for (int r = 0; r < 4; ++r) {
            const int q = q0 + quad * 4 + r;
            const bool qs = q < NK;
            const int cls = qs ? idivf(q, Kc, rKc) : 20;
            gr[r] = gch + (size_t)cls * 512 + kb0 + 2 * l16;
            dq[r] = qs ? q : -1;
        }
        f32x2 gpre[16];
        #pragma unroll
        for (int r = 0; r < 4; ++r)
            #pragma unroll
            for (int c = 0; c < 4; ++c)
                gpre[r * 4 + c] = *(const f32x2*)(gr[r] + c * 32);

        // ---- exp2 + partial row sums (this wave's 128 keys) ----
        float ls[4] = {0.f, 0.f, 0.f, 0.f};
        #pragma unroll
        for (int j = 0; j < 8; ++j) {
            #pragma unroll
            for (int r = 0; r < 4; ++r) {
                const float e = exp2_fast(sc[j][r]);
                sc[j][r] = e;
                ls[r] += e;
            }
        }
        #pragma unroll
        for (int r = 0; r < 4; ++r) {
            ls[r] += __shfl_xor(ls[r], 1, 64);
            ls[r] += __shfl_xor(ls[r], 2, 64);
            ls[r] += __shfl_xor(ls[r], 4, 64);
            ls[r] += __shfl_xor(ls[r], 8, 64);
        }
        if (l16 == 0) {
            #pragma unroll
            for (int r = 0; r < 4; ++r) Lw[bsel][quad * 4 + r][wave] = ls[r];
        }

        // ---- gate (diagonal cndmask fix) + cvt_pk -> packed b32 P writes ----
        #pragma unroll
        for (int c = 0; c < 4; ++c) {
            const int key0 = kb0 + c * 32 + l16, key1 = key0 + 16;
            #pragma unroll
            for (int r = 0; r < 4; ++r) {
                const f32x2 g = gpre[r * 4 + c];
                const float gx = (key0 == dq[r]) ? g0 : g.x;
                const float gy = (key1 == dq[r]) ? g0 : g.y;
                const float p0 = sc[2 * c][r] * gx;
                const float p1 = sc[2 * c + 1][r] * gy;
                unsigned int pk;
                asm("v_cvt_pk_bf16_f32 %0, %1, %2" : "=v"(pk) : "v"(p0), "v"(p1));
                *(unsigned int*)(&Pb[bsel][quad * 4 + r][kb0 + c * 32 + 2 * l16]) = pk;
            }
        }
        __syncthreads();

        // ---- PV: P from LDS (issue all 16 reads), V from registers ----
        const short* Prow = &Pb[bsel][l16][quad * 8];
        short8 ap[16];
        #pragma unroll
        for (int ks = 0; ks < 16; ++ks) ap[ks] = *(const short8*)(Prow + ks * 32);
        f32x4 O0 = (f32x4){0.f, 0.f, 0.f, 0.f}, O1 = (f32x4){0.f, 0.f, 0.f, 0.f};
        #pragma unroll
        for (int ks = 0; ks < 16; ks += 2) {
            O0 = __builtin_amdgcn_mfma_f32_16x16x32_bf16(ap[ks], vf[ks], O0, 0, 0, 0);
            O1 = __builtin_amdgcn_mfma_f32_16x16x32_bf16(ap[ks + 1], vf[ks + 1], O1, 0, 0, 0);
        }
        const f32x4 O = O0 + O1;

        // ---- epilogue: divide by global l, write bf16 ----
        #pragma unroll
        for (int r = 0; r < 4; ++r) {
            const int q = quad * 4 + r;
            const int s = q0 + q;
            if (s < S) {
                const f32x4 lv = *(const f32x4*)Lw[bsel][q];
                const float lq = (lv[0] + lv[1]) + (lv[2] + lv[3]);
                out[((size_t)b * S + s) * D + h * 64 + dsl + l16] =
                    f2bf(O[r] * __builtin_amdgcn_rcpf(lq));
            }
        }
    }
}

extern "C" void kernel_launch(void* const* d_in, const int* in_sizes, int n_in,
                              void* d_out, int out_size, void* d_ws, size_t ws_size,
                              hipStream_t stream)
{
    const float* samples = (const float*)d_in[0];
    const float* Wq      = (const float*)d_in[1];
    const float* Wk      = (const float*)d_in[2];
    const float* Wv      = (const float*)d_in[3];
    const float* attn_w  = (const float*)d_in[4];
    const float* fc_w    = (const float*)d_in[5];
    const float* fc_b    = (const float*)d_in[6];
    const float* mha_g   = (const float*)d_in[7];
    const float* mha_b   = (const float*)d_in[8];
    const float* w1      = (const float*)d_in[9];
    const float* b1      = (const float*)d_in[10];
    const float* w2      = (const float*)d_in[11];
    const float* b2      = (const float*)d_in[12];
    const float* dg      = (const float*)d_in[13];
    const float* db      = (const float*)d_in[14];
    const float* ow      = (const float*)d_in[15];
    const float* ob      = (const float*)d_in[16];
    const float* og      = (const float*)d_in[17];
    const float* obeta   = (const float*)d_in[18];
    const int*   Kp      = (const int*)d_in[20];

    const int Bsz = 128;
    const int S = in_sizes[0] / (Bsz * D);   // 501
    const int rows = Bsz * S;                // 64128
    const size_t n_el = (size_t)rows * D;
    const size_t n_pad = (size_t)Bsz * H * SPAD * 64;

    float* x   = (float*)d_out;
    short* xb  = (short*)d_ws;               // bf16 activations [rows][D]
    short* aob = xb + n_el;                  // attn out bf16; aliased as Vb and later hb
    short* hb  = aob;
    short* Vb  = aob;                        // row-major V [B*H][S][64], exactly n_el shorts
    short* Qb  = aob + n_el;                 // [B*H][512][64]
    short* Kb  = Qb + n_pad;                 // [B*H][512][64]
    short* Vt  = Kb + n_pad;                 // [B*H][64][512] (key-permuted)
    short* wts = Vt + n_pad;
    float* gcls = (float*)(wts + (size_t)NMAT * 65536);   // [L][H][21][512] f32, 344 KB

    PackArgs pa;
    for (int l = 0; l < 2; ++l) {
        const size_t wo = (size_t)l * 65536;
        pa.src[l*6 + 0] = Wq + wo;   pa.scale[l*6 + 0] = 0.125f * LOG2E;  // temp + log2e fold
        pa.src[l*6 + 1] = Wk + wo;   pa.scale[l*6 + 1] = 1.f;
        pa.src[l*6 + 2] = Wv + wo;   pa.scale[l*6 + 2] = 1.f;
        pa.src[l*6 + 3] = fc_w + wo; pa.scale[l*6 + 3] = 1.f;
        pa.src[l*6 + 4] = w1 + wo;   pa.scale[l*6 + 4] = 1.f;
        pa.src[l*6 + 5] = w2 + wo;   pa.scale[l*6 + 5] = 1.f;
    }
    pa.src[12] = ow; pa.scale[12] = 1.f;
    pa.dst = wts;
    pack_kernel<<<dim3(256, NMAT), 256, 0, stream>>>(pa);

    gate_cls_kernel<<<dim3(42, H, 2), 256, 0, stream>>>(attn_w, Kp, gcls, S);

    copy_cast_kernel<<<(int)((n_el / 4 + 255) / 256), 256, 0, stream>>>(samples, x, xb, (long)n_el);

    const int gblocks = rows / 64;           // 1002
    for (int l = 0; l < 2; ++l) {
        short* wl = wts + (size_t)l * 6 * 65536;
        qkv_gemm_kernel<<<gblocks, 256, 0, stream>>>(xb, wl, Qb, Kb, Vb, S);
        vt_transpose_kernel<<<dim3(8, Bsz * H), 256, 0, stream>>>(Vb, Vt, S);
        attn_kernel<<<Bsz * H, 256, 0, stream>>>(Qb, Kb, Vt,
                                              gcls + (size_t)l * H * 21 * 512,
                                              attn_w + (size_t)l * H * 6, Kp, aob, S);
        gemm_res_ln_kernel<<<gblocks, 256, 0, stream>>>(aob, wl + 3 * 65536,
                                              fc_b + (size_t)l * D, x,
                                              mha_g + (size_t)l * D, mha_b + (size_t)l * D,
                                              x, xb);
        gemm_relu_kernel<<<gblocks, 256, 0, stream>>>(xb, wl + 4 * 65536,
                                              b1 + (size_t)l * D, hb);
        gemm_res_ln_kernel<<<gblocks, 256, 0, stream>>>(hb, wl + 5 * 65536,
                                              b2 + (size_t)l * D, x,
                                              dg + (size_t)l * D, db + (size_t)l * D,
                                              x, xb);
    }
    gemm_res_ln_kernel<<<gblocks, 256, 0, stream>>>(xb, wts + 12 * 65536,
                                              ob, samples, og, obeta, x, xb);
}

// Round 7
// 769.298 us; speedup vs baseline: 2.1761x; 1.1049x over previous
//
#include <hip/hip_runtime.h>
#include <cstdint>
#include <cstddef>
#include <cmath>

#define D 256
#define H 4
#define LN_EPS 1e-5f
#define SPAD 512
#define NMAT 13
#define PBS 520   // Pb row stride in shorts: 1040 B = 65*16 (aligned), 260 words
#define LOG2E 1.44269504088896340736f

typedef __attribute__((ext_vector_type(8))) short short8;
typedef __attribute__((ext_vector_type(4))) short short4v;
typedef __attribute__((ext_vector_type(4))) float f32x4;
typedef __attribute__((ext_vector_type(2))) float f32x2;
typedef __attribute__((ext_vector_type(4))) int i32x4;

static __device__ __forceinline__ short f2bf(float f) {
    union { float f; unsigned u; } a; a.f = f;
    unsigned r = a.u + 0x7fffu + ((a.u >> 16) & 1u);
    return (short)(r >> 16);
}

static __device__ __forceinline__ float exp2_fast(float x) {
#if __has_builtin(__builtin_amdgcn_exp2f)
    return __builtin_amdgcn_exp2f(x);
#else
    float r; asm("v_exp_f32 %0, %1" : "=v"(r) : "v"(x)); return r;
#endif
}

// exact int divide by small runtime divisor via float reciprocal + correction
static __device__ __forceinline__ int idivf(int x, int Kc, float rKc) {
    int q = (int)((float)x * rKc);
    q -= (q * Kc > x) ? 1 : 0;
    q += ((q + 1) * Kc <= x) ? 1 : 0;
    return q;
}

// ---------- pack fp32 W[k][n] -> bf16 fragment-ordered B ----------
struct PackArgs { const float* src[NMAT]; float scale[NMAT]; short* dst; };

__global__ __launch_bounds__(256)
void pack_kernel(PackArgs pa)
{
    const int mat = blockIdx.y;
    const int el = blockIdx.x * 256 + threadIdx.x;
    const int n = el & 255, k = el >> 8;
    const int nt = n >> 4, l16 = n & 15;
    const int kc = k >> 5, qd = (k >> 3) & 3, j = k & 7;
    const size_t didx = (((size_t)(kc * 16 + nt) * 64) + qd * 16 + l16) * 8 + j;
    pa.dst[(size_t)mat * 65536 + didx] =
        f2bf(pa.src[mat][(size_t)k * 256 + n] * pa.scale[mat]);
}

// ---------- gate CLASS table: gc[l][h][cls][pos], cls = q/Kc (0..19) or 20 (query row) ----------
// pos is the PERMUTED key index: within each 32-block, key = 16*(pos&1) + ((pos>>1)&15).
// Diagonal (key==q -> g0) is NOT baked; fixed in attn with a cndmask.
__global__ __launch_bounds__(256)
void gate_cls_kernel(const float* __restrict__ aw, const int* __restrict__ Kp,
                     float* __restrict__ gc, int S)
{
    const int idx = blockIdx.x * 256 + threadIdx.x;   // cls*512 + pos, 21*512 = 10752
    const int h = blockIdx.y, l = blockIdx.z;
    const int cls = idx >> 9, pos = idx & 511;
    const int key = (pos & ~31) | ((pos & 1) << 4) | ((pos >> 1) & 15);
    const int NK = S - 1;
    const int Kc = Kp[0];
    int cat;
    if (cls < 20) cat = (key == NK) ? 3 : ((key < NK && key / Kc == cls) ? 1 : 2);
    else          cat = (key == NK) ? 5 : 4;
    gc[((size_t)(l * H + h) * 21 + cls) * 512 + pos] = tanhf(aw[(l * H + h) * 6 + cat]);
}

// ---------- bf16 cast only (fp32 copy dropped: layer-0 residual reads samples directly) ----------
__global__ __launch_bounds__(256)
void cast_kernel(const float* __restrict__ x, short* __restrict__ xb, long n)
{
    const long i = ((long)blockIdx.x * 256 + threadIdx.x) * 4;
    if (i >= n) return;
    const f32x4 v = *(const f32x4*)(x + i);
    short4v o;
    o.x = f2bf(v.x); o.y = f2bf(v.y); o.z = f2bf(v.z); o.w = f2bf(v.w);
    *(short4v*)(xb + i) = o;
}

// ---------- MFMA mainloop, 512-thread blocks: 8 waves x 16 rows, 256 cols, K=256 ----------
// B fragment-ordered => each 32-K chunk is a LINEAR 16 KB block, staged through
// double-buffered LDS by all 512 threads (2 x short8 each). 128 rows share one
// B-staging (was 64) => half the stagings/barriers per output row.
static __device__ __forceinline__ void gemm_tile_lds(const short* __restrict__ A,
                                                     const short* __restrict__ Bt,
                                                     short (&Bs)[2][8192],
                                                     int rowA, int tid, int lane, int quad,
                                                     f32x4 (&acc)[16])
{
    const short* Ar = A + (size_t)rowA * D + quad * 8;
    #pragma unroll
    for (int nt = 0; nt < 16; ++nt) acc[nt] = (f32x4){0.f, 0.f, 0.f, 0.f};
    {
        const short8* src = (const short8*)Bt + tid;
        short8* dst = (short8*)Bs[0] + tid;
        dst[0] = src[0]; dst[512] = src[512];
    }
    __syncthreads();
    #pragma unroll
    for (int kc = 0; kc < 8; ++kc) {
        short8 stg0, stg1;
        if (kc < 7) {
            const short8* src = (const short8*)(Bt + (size_t)(kc + 1) * 8192) + tid;
            stg0 = src[0]; stg1 = src[512];
        }
        const short8 af = *(const short8*)(Ar + kc * 32);
        const short* Bl = Bs[kc & 1] + lane * 8;
        #pragma unroll
        for (int nt = 0; nt < 16; ++nt) {
            const short8 bf = *(const short8*)(Bl + nt * 512);
            acc[nt] = __builtin_amdgcn_mfma_f32_16x16x32_bf16(af, bf, acc[nt], 0, 0, 0);
        }
        if (kc < 7) {
            short8* dst = (short8*)Bs[(kc + 1) & 1] + tid;
            dst[0] = stg0; dst[512] = stg1;
        }
        __syncthreads();
    }
}

// ---------- GEMM + bias + residual + LayerNorm, writes fp32 + bf16 ----------
__global__ __launch_bounds__(512)
void gemm_res_ln_kernel(const short* __restrict__ A, const short* __restrict__ Bt,
                        const float* __restrict__ bias, const float* __restrict__ resid,
                        const float* __restrict__ gam, const float* __restrict__ bet,
                        float* __restrict__ xout, short* __restrict__ xbout)
{
    const int tid = threadIdx.x, wave = tid >> 6, lane = tid & 63;
    const int l16 = lane & 15, quad = lane >> 4;
    const int row0 = blockIdx.x * 128 + wave * 16;
    __shared__ __align__(16) short Bs[2][8192];
    f32x4 acc[16];
    gemm_tile_lds(A, Bt, Bs, row0 + l16, tid, lane, quad, acc);

    #pragma unroll
    for (int nt = 0; nt < 16; ++nt) {
        const int col = nt * 16 + l16;
        const float bl = bias[col];
        #pragma unroll
        for (int r = 0; r < 4; ++r)
            acc[nt][r] += bl + resid[(size_t)(row0 + quad * 4 + r) * D + col];
    }
    float mu[4], rstd[4];
    #pragma unroll
    for (int r = 0; r < 4; ++r) {
        float s = 0.f;
        #pragma unroll
        for (int nt = 0; nt < 16; ++nt) s += acc[nt][r];
        s += __shfl_xor(s, 1, 64); s += __shfl_xor(s, 2, 64);
        s += __shfl_xor(s, 4, 64); s += __shfl_xor(s, 8, 64);
        mu[r] = s * (1.f / D);
        float q = 0.f;
        #pragma unroll
        for (int nt = 0; nt < 16; ++nt) { const float d = acc[nt][r] - mu[r]; q = fmaf(d, d, q); }
        q += __shfl_xor(q, 1, 64); q += __shfl_xor(q, 2, 64);
        q += __shfl_xor(q, 4, 64); q += __shfl_xor(q, 8, 64);
        rstd[r] = rsqrtf(q * (1.f / D) + LN_EPS);
    }
    #pragma unroll
    for (int nt = 0; nt < 16; ++nt) {
        const int col = nt * 16 + l16;
        const float g = gam[col], be = bet[col];
        #pragma unroll
        for (int r = 0; r < 4; ++r) {
            const size_t idx = (size_t)(row0 + quad * 4 + r) * D + col;
            const float o = (acc[nt][r] - mu[r]) * rstd[r] * g + be;
            xout[idx] = o;
            xbout[idx] = f2bf(o);
        }
    }
}

// ---------- GEMM + bias + relu -> bf16 ----------
__global__ __launch_bounds__(512)
void gemm_relu_kernel(const short* __restrict__ A, const short* __restrict__ Bt,
                      const float* __restrict__ bias, short* __restrict__ hb)
{
    const int tid = threadIdx.x, wave = tid >> 6, lane = tid & 63;
    const int l16 = lane & 15, quad = lane >> 4;
    const int row0 = blockIdx.x * 128 + wave * 16;
    __shared__ __align__(16) short Bs[2][8192];
    f32x4 acc[16];
    gemm_tile_lds(A, Bt, Bs, row0 + l16, tid, lane, quad, acc);
    #pragma unroll
    for (int nt = 0; nt < 16; ++nt) {
        const int col = nt * 16 + l16;
        const float bl = bias[col];
        #pragma unroll
        for (int r = 0; r < 4; ++r)
            hb[(size_t)(row0 + quad * 4 + r) * D + col] = f2bf(fmaxf(acc[nt][r] + bl, 0.f));
    }
}

// ---------- QKV: three GEMMs. Q,K padded layouts; V ROW-MAJOR (coalesced) ----------
__global__ __launch_bounds__(512)
void qkv_gemm_kernel(const short* __restrict__ A, const short* __restrict__ Wt,
                     short* __restrict__ Qb, short* __restrict__ Kb,
                     short* __restrict__ Vb, int S)
{
    const int tid = threadIdx.x, wave = tid >> 6, lane = tid & 63;
    const int l16 = lane & 15, quad = lane >> 4;
    const int row0 = blockIdx.x * 128 + wave * 16;
    __shared__ __align__(16) short Bs[2][8192];
    int bb[4], ss[4];
    #pragma unroll
    for (int r = 0; r < 4; ++r) {
        const int row = row0 + quad * 4 + r;
        bb[r] = row / S; ss[r] = row - bb[r] * S;
    }
    #pragma unroll 1
    for (int m = 0; m < 3; ++m) {
        f32x4 acc[16];
        gemm_tile_lds(A, Wt + (size_t)m * 65536, Bs, row0 + l16, tid, lane, quad, acc);
        #pragma unroll
        for (int nt = 0; nt < 16; ++nt) {
            const int col = nt * 16 + l16, h = col >> 6, dim = col & 63;
            #pragma unroll
            for (int r = 0; r < 4; ++r) {
                const int bh = bb[r] * H + h;
                const short v = f2bf(acc[nt][r]);
                if (m == 0)      Qb[((size_t)bh * SPAD + ss[r]) * 64 + dim] = v;
                else if (m == 1) Kb[((size_t)bh * SPAD + ss[r]) * 64 + dim] = v;
                else             Vb[((size_t)bh * S + ss[r]) * 64 + dim] = v;   // row-major, unpadded
            }
        }
    }
}

// ---------- V transpose: [bh][s][64] -> Vt[bh][64][pos] (permuted, padded, zero tail) ----------
__global__ __launch_bounds__(256)
void vt_transpose_kernel(const short* __restrict__ Vb, short* __restrict__ Vt, int S)
{
    const int bh = blockIdx.y;
    const int s0 = blockIdx.x * 64;
    const int t = threadIdx.x;
    __shared__ short T[64][72];
    {
        const int r = t >> 2, c = (t & 3) * 16;
        const int s = s0 + r;
        short8 v0 = (short8){0,0,0,0,0,0,0,0}, v1 = (short8){0,0,0,0,0,0,0,0};
        if (s < S) {
            const short* src = Vb + ((size_t)bh * S + s) * 64 + c;
            v0 = *(const short8*)src;
            v1 = *(const short8*)(src + 8);
        }
        *(short8*)&T[r][c] = v0;
        *(short8*)&T[r][c + 8] = v1;
    }
    __syncthreads();
    {
        const int dim = t >> 2, g = t & 3;
        int w[8];
        #pragma unroll
        for (int j = 0; j < 8; ++j) {
            const int d = g * 8 + j;                       // dword index 0..31 in this 64-span
            const int k0 = ((d >> 4) << 5) | (d & 15);     // key row in tile (pair partner +16)
            const unsigned lo = (unsigned short)T[k0][dim];
            const unsigned hi = (unsigned short)T[k0 + 16][dim];
            w[j] = (int)(lo | (hi << 16));
        }
        int* dst = (int*)(Vt + ((size_t)bh * 64 + dim) * SPAD + s0) + g * 8;
        *(i32x4*)dst = (i32x4){w[0], w[1], w[2], w[3]};
        *(i32x4*)(dst + 4) = (i32x4){w[4], w[5], w[6], w[7]};
    }
}

// ---------------- MFMA attention: (b,h) x q-half blocks, K+V resident in REGISTERS ----------------
// grid = dim3(B*H, 2): each block owns one bh and HALF the q-range (16 q-tiles).
// Doubles resident blocks (2->4 per CU, occupancy ~20%->~39%) to hide the per-iter
// VALU+LDS chain; K/V register residency amortized over 16 iters instead of 32.
// Wave w: keys [w*128,w*128+128) for QK, d-slice [w*16,w*16+16) for PV.
__global__ __launch_bounds__(256, 2)
void attn_kernel(const short* __restrict__ Qb, const short* __restrict__ Kb,
                 const short* __restrict__ Vt, const float* __restrict__ gc,
                 const float* __restrict__ awl, const int* __restrict__ Kp,
                 short* __restrict__ out, int S)
{
    const int bh = blockIdx.x;
    const int qh = blockIdx.y;
    const int b = bh >> 2, h = bh & 3;
    const int tid = threadIdx.x;
    const int wave = tid >> 6, lane = tid & 63;
    const int l16 = lane & 15, quad = lane >> 4;
    const int NK = S - 1;
    const int Kc = Kp[0];
    const float rKc = 1.0f / (float)Kc;
    const float g0 = tanhf(awl[h * 6]);

    __shared__ __align__(16) float Lw[2][16][4];
    __shared__ __align__(16) short Pb[2][16][PBS];

    const int kb0 = wave * 128;
    const short* Kbh = Kb + (size_t)bh * SPAD * 64;
    const short* Vbh = Vt + (size_t)bh * 64 * SPAD;
    const float* gch = gc + (size_t)h * (21 * 512);
    const int dsl = wave * 16;
    const short* Vrow = Vbh + (size_t)(dsl + l16) * SPAD + quad * 8;

    // ---- hoisted: wave's 128-key K-span (64 VGPR) + 16-dim V-slice (64 VGPR) ----
    short8 kf[16];
    #pragma unroll
    for (int c = 0; c < 4; ++c) {
        const size_t kr = (size_t)(kb0 + c * 32 + l16) * 64 + quad * 8;
        kf[4 * c + 0] = *(const short8*)(Kbh + kr);
        kf[4 * c + 1] = *(const short8*)(Kbh + kr + 32);
        kf[4 * c + 2] = *(const short8*)(Kbh + kr + 16 * 64);
        kf[4 * c + 3] = *(const short8*)(Kbh + kr + 16 * 64 + 32);
    }
    short8 vf[16];
    #pragma unroll
    for (int ks = 0; ks < 16; ++ks) vf[ks] = *(const short8*)(Vrow + ks * 32);

    #pragma unroll 1
    for (int it = 0; it < 16; ++it) {
        const int q0 = (qh * 16 + it) << 4;
        const int bsel = it & 1;

        // ---- Q frags for this q-tile ----
        const size_t qrow = ((size_t)bh * SPAD + q0 + l16) * 64;
        const short8 aq0 = *(const short8*)(Qb + qrow + quad * 8);
        const short8 aq1 = *(const short8*)(Qb + qrow + 32 + quad * 8);

        // ---- QK^T from registers ----
        f32x4 sc[8];
        #pragma unroll
        for (int c = 0; c < 4; ++c) {
            const int kbase = kb0 + c * 32;
            f32x4 s0 = (f32x4){0.f, 0.f, 0.f, 0.f}, s1 = (f32x4){0.f, 0.f, 0.f, 0.f};
            s0 = __builtin_amdgcn_mfma_f32_16x16x32_bf16(aq0, kf[4 * c + 0], s0, 0, 0, 0);
            s0 = __builtin_amdgcn_mfma_f32_16x16x32_bf16(aq1, kf[4 * c + 1], s0, 0, 0, 0);
            s1 = __builtin_amdgcn_mfma_f32_16x16x32_bf16(aq0, kf[4 * c + 2], s1, 0, 0, 0);
            s1 = __builtin_amdgcn_mfma_f32_16x16x32_bf16(aq1, kf[4 * c + 3], s1, 0, 0, 0);
            if (kbase + 32 > S) {
                const bool v0 = (kbase + l16) < S, v1 = (kbase + 16 + l16) < S;
                #pragma unroll
                for (int r = 0; r < 4; ++r) {
                    s0[r] = v0 ? s0[r] : -INFINITY;
                    s1[r] = v1 ? s1[r] : -INFINITY;
                }
            }
            sc[2 * c] = s0; sc[2 * c + 1] = s1;
        }

        // ---- gate prefetch from class table (L2-hot) ----
        int dq[4]; const float* gr[4];
        #pragma unroll
        for (int r = 0; r < 4; ++r) {
            const int q = q0 + quad * 4 + r;
            const bool qs = q < NK;
            const int cls = qs ? idivf(q, Kc, rKc) : 20;
            gr[r] = gch + (size_t)cls * 512 + kb0 + 2 * l16;
            dq[r] = qs ? q : -1;
        }
        f32x2 gpre[16];
        #pragma unroll
        for (int r = 0; r < 4; ++r)
            #pragma unroll
            for (int c = 0; c < 4; ++c)
                gpre[r * 4 + c] = *(const f32x2*)(gr[r] + c * 32);

        // ---- exp2 + partial row sums (this wave's 128 keys) ----
        float ls[4] = {0.f, 0.f, 0.f, 0.f};
        #pragma unroll
        for (int j = 0; j < 8; ++j) {
            #pragma unroll
            for (int r = 0; r < 4; ++r) {
                const float e = exp2_fast(sc[j][r]);
                sc[j][r] = e;
                ls[r] += e;
            }
        }
        #pragma unroll
        for (int r = 0; r < 4; ++r) {
            ls[r] += __shfl_xor(ls[r], 1, 64);
            ls[r] += __shfl_xor(ls[r], 2, 64);
            ls[r] += __shfl_xor(ls[r], 4, 64);
            ls[r] += __shfl_xor(ls[r], 8, 64);
        }
        if (l16 == 0) {
            #pragma unroll
            for (int r = 0; r < 4; ++r) Lw[bsel][quad * 4 + r][wave] = ls[r];
        }

        // ---- gate (diagonal cndmask fix) + cvt_pk -> packed b32 P writes ----
        #pragma unroll
        for (int c = 0; c < 4; ++c) {
            const int key0 = kb0 + c * 32 + l16, key1 = key0 + 16;
            #pragma unroll
            for (int r = 0; r < 4; ++r) {
                const f32x2 g = gpre[r * 4 + c];
                const float gx = (key0 == dq[r]) ? g0 : g.x;
                const float gy = (key1 == dq[r]) ? g0 : g.y;
                const float p0 = sc[2 * c][r] * gx;
                const float p1 = sc[2 * c + 1][r] * gy;
                unsigned int pk;
                asm("v_cvt_pk_bf16_f32 %0, %1, %2" : "=v"(pk) : "v"(p0), "v"(p1));
                *(unsigned int*)(&Pb[bsel][quad * 4 + r][kb0 + c * 32 + 2 * l16]) = pk;
            }
        }
        __syncthreads();

        // ---- PV: P from LDS (issue all 16 reads), V from registers ----
        const short* Prow = &Pb[bsel][l16][quad * 8];
        short8 ap[16];
        #pragma unroll
        for (int ks = 0; ks < 16; ++ks) ap[ks] = *(const short8*)(Prow + ks * 32);
        f32x4 O0 = (f32x4){0.f, 0.f, 0.f, 0.f}, O1 = (f32x4){0.f, 0.f, 0.f, 0.f};
        #pragma unroll
        for (int ks = 0; ks < 16; ks += 2) {
            O0 = __builtin_amdgcn_mfma_f32_16x16x32_bf16(ap[ks], vf[ks], O0, 0, 0, 0);
            O1 = __builtin_amdgcn_mfma_f32_16x16x32_bf16(ap[ks + 1], vf[ks + 1], O1, 0, 0, 0);
        }
        const f32x4 O = O0 + O1;

        // ---- epilogue: divide by global l, write bf16 ----
        #pragma unroll
        for (int r = 0; r < 4; ++r) {
            const int q = quad * 4 + r;
            const int s = q0 + q;
            if (s < S) {
                const f32x4 lv = *(const f32x4*)Lw[bsel][q];
                const float lq = (lv[0] + lv[1]) + (lv[2] + lv[3]);
                out[((size_t)b * S + s) * D + h * 64 + dsl + l16] =
                    f2bf(O[r] * __builtin_amdgcn_rcpf(lq));
            }
        }
    }
}

extern "C" void kernel_launch(void* const* d_in, const int* in_sizes, int n_in,
                              void* d_out, int out_size, void* d_ws, size_t ws_size,
                              hipStream_t stream)
{
    const float* samples = (const float*)d_in[0];
    const float* Wq      = (const float*)d_in[1];
    const float* Wk      = (const float*)d_in[2];
    const float* Wv      = (const float*)d_in[3];
    const float* attn_w  = (const float*)d_in[4];
    const float* fc_w    = (const float*)d_in[5];
    const float* fc_b    = (const float*)d_in[6];
    const float* mha_g   = (const float*)d_in[7];
    const float* mha_b   = (const float*)d_in[8];
    const float* w1      = (const float*)d_in[9];
    const float* b1      = (const float*)d_in[10];
    const float* w2      = (const float*)d_in[11];
    const float* b2      = (const float*)d_in[12];
    const float* dg      = (const float*)d_in[13];
    const float* db      = (const float*)d_in[14];
    const float* ow      = (const float*)d_in[15];
    const float* ob      = (const float*)d_in[16];
    const float* og      = (const float*)d_in[17];
    const float* obeta   = (const float*)d_in[18];
    const int*   Kp      = (const int*)d_in[20];

    const int Bsz = 128;
    const int S = in_sizes[0] / (Bsz * D);   // 501
    const int rows = Bsz * S;                // 64128
    const size_t n_el = (size_t)rows * D;
    const size_t n_pad = (size_t)Bsz * H * SPAD * 64;

    float* x   = (float*)d_out;
    short* xb  = (short*)d_ws;               // bf16 activations [rows][D]
    short* aob = xb + n_el;                  // attn out bf16; aliased as Vb and later hb
    short* hb  = aob;
    short* Vb  = aob;                        // row-major V [B*H][S][64], exactly n_el shorts
    short* Qb  = aob + n_el;                 // [B*H][512][64]
    short* Kb  = Qb + n_pad;                 // [B*H][512][64]
    short* Vt  = Kb + n_pad;                 // [B*H][64][512] (key-permuted)
    short* wts = Vt + n_pad;
    float* gcls = (float*)(wts + (size_t)NMAT * 65536);   // [L][H][21][512] f32, 344 KB

    PackArgs pa;
    for (int l = 0; l < 2; ++l) {
        const size_t wo = (size_t)l * 65536;
        pa.src[l*6 + 0] = Wq + wo;   pa.scale[l*6 + 0] = 0.125f * LOG2E;  // temp + log2e fold
        pa.src[l*6 + 1] = Wk + wo;   pa.scale[l*6 + 1] = 1.f;
        pa.src[l*6 + 2] = Wv + wo;   pa.scale[l*6 + 2] = 1.f;
        pa.src[l*6 + 3] = fc_w + wo; pa.scale[l*6 + 3] = 1.f;
        pa.src[l*6 + 4] = w1 + wo;   pa.scale[l*6 + 4] = 1.f;
        pa.src[l*6 + 5] = w2 + wo;   pa.scale[l*6 + 5] = 1.f;
    }
    pa.src[12] = ow; pa.scale[12] = 1.f;
    pa.dst = wts;
    pack_kernel<<<dim3(256, NMAT), 256, 0, stream>>>(pa);

    gate_cls_kernel<<<dim3(42, H, 2), 256, 0, stream>>>(attn_w, Kp, gcls, S);

    cast_kernel<<<(int)((n_el / 4 + 255) / 256), 256, 0, stream>>>(samples, xb, (long)n_el);

    const int gblocks = rows / 128;          // 501
    for (int l = 0; l < 2; ++l) {
        short* wl = wts + (size_t)l * 6 * 65536;
        const float* layer_in = (l == 0) ? samples : x;   // fp32 residual source
        qkv_gemm_kernel<<<gblocks, 512, 0, stream>>>(xb, wl, Qb, Kb, Vb, S);
        vt_transpose_kernel<<<dim3(8, Bsz * H), 256, 0, stream>>>(Vb, Vt, S);
        attn_kernel<<<dim3(Bsz * H, 2), 256, 0, stream>>>(Qb, Kb, Vt,
                                              gcls + (size_t)l * H * 21 * 512,
                                              attn_w + (size_t)l * H * 6, Kp, aob, S);
        gemm_res_ln_kernel<<<gblocks, 512, 0, stream>>>(aob, wl + 3 * 65536,
                                              fc_b + (size_t)l * D, layer_in,
                                              mha_g + (size_t)l * D, mha_b + (size_t)l * D,
                                              x, xb);
        gemm_relu_kernel<<<gblocks, 512, 0, stream>>>(xb, wl + 4 * 65536,
                                              b1 + (size_t)l * D, hb);
        gemm_res_ln_kernel<<<gblocks, 512, 0, stream>>>(hb, wl + 5 * 65536,
                                              b2 + (size_t)l * D, x,
                                              dg + (size_t)l * D, db + (size_t)l * D,
                                              x, xb);
    }
    gemm_res_ln_kernel<<<gblocks, 512, 0, stream>>>(xb, wts + 12 * 65536,
                                              ob, samples, og, obeta, x, xb);
}

// Round 8
// 760.729 us; speedup vs baseline: 2.2006x; 1.0113x over previous
//
#include <hip/hip_runtime.h>
#include <cstdint>
#include <cstddef>
#include <cmath>

#define D 256
#define H 4
#define LN_EPS 1e-5f
#define SPAD 512
#define NMAT 13
#define PBS 520   // Pb row stride in shorts: 1040 B = 65*16 (aligned), 260 words
#define LOG2E 1.44269504088896340736f

typedef __attribute__((ext_vector_type(8))) short short8;
typedef __attribute__((ext_vector_type(4))) short short4v;
typedef __attribute__((ext_vector_type(4))) float f32x4;
typedef __attribute__((ext_vector_type(2))) float f32x2;
typedef __attribute__((ext_vector_type(4))) int i32x4;

static __device__ __forceinline__ short f2bf(float f) {
    union { float f; unsigned u; } a; a.f = f;
    unsigned r = a.u + 0x7fffu + ((a.u >> 16) & 1u);
    return (short)(r >> 16);
}

static __device__ __forceinline__ float exp2_fast(float x) {
#if __has_builtin(__builtin_amdgcn_exp2f)
    return __builtin_amdgcn_exp2f(x);
#else
    float r; asm("v_exp_f32 %0, %1" : "=v"(r) : "v"(x)); return r;
#endif
}

// exact int divide by small runtime divisor via float reciprocal + correction
static __device__ __forceinline__ int idivf(int x, int Kc, float rKc) {
    int q = (int)((float)x * rKc);
    q -= (q * Kc > x) ? 1 : 0;
    q += ((q + 1) * Kc <= x) ? 1 : 0;
    return q;
}

// ---------- pack fp32 W[k][n] -> bf16 fragment-ordered B ----------
struct PackArgs { const float* src[NMAT]; float scale[NMAT]; short* dst; };

__global__ __launch_bounds__(256)
void pack_kernel(PackArgs pa)
{
    const int mat = blockIdx.y;
    const int el = blockIdx.x * 256 + threadIdx.x;
    const int n = el & 255, k = el >> 8;
    const int nt = n >> 4, l16 = n & 15;
    const int kc = k >> 5, qd = (k >> 3) & 3, j = k & 7;
    const size_t didx = (((size_t)(kc * 16 + nt) * 64) + qd * 16 + l16) * 8 + j;
    pa.dst[(size_t)mat * 65536 + didx] =
        f2bf(pa.src[mat][(size_t)k * 256 + n] * pa.scale[mat]);
}

// ---------- gate CLASS table: gc[l][h][cls][pos], cls = q/Kc (0..19) or 20 (query row) ----------
// pos is the PERMUTED key index: within each 32-block, key = 16*(pos&1) + ((pos>>1)&15).
// Diagonal (key==q -> g0) is NOT baked; fixed in attn with a cndmask.
__global__ __launch_bounds__(256)
void gate_cls_kernel(const float* __restrict__ aw, const int* __restrict__ Kp,
                     float* __restrict__ gc, int S)
{
    const int idx = blockIdx.x * 256 + threadIdx.x;   // cls*512 + pos, 21*512 = 10752
    const int h = blockIdx.y, l = blockIdx.z;
    const int cls = idx >> 9, pos = idx & 511;
    const int key = (pos & ~31) | ((pos & 1) << 4) | ((pos >> 1) & 15);
    const int NK = S - 1;
    const int Kc = Kp[0];
    int cat;
    if (cls < 20) cat = (key == NK) ? 3 : ((key < NK && key / Kc == cls) ? 1 : 2);
    else          cat = (key == NK) ? 5 : 4;
    gc[((size_t)(l * H + h) * 21 + cls) * 512 + pos] = tanhf(aw[(l * H + h) * 6 + cat]);
}

// ---------- bf16 cast only (fp32 copy dropped: layer-0 residual reads samples directly) ----------
__global__ __launch_bounds__(256)
void cast_kernel(const float* __restrict__ x, short* __restrict__ xb, long n)
{
    const long i = ((long)blockIdx.x * 256 + threadIdx.x) * 4;
    if (i >= n) return;
    const f32x4 v = *(const f32x4*)(x + i);
    short4v o;
    o.x = f2bf(v.x); o.y = f2bf(v.y); o.z = f2bf(v.z); o.w = f2bf(v.w);
    *(short4v*)(xb + i) = o;
}

// ---------- MFMA mainloop, 512-thread blocks: 8 waves x 16 rows, 256 cols, K=256 ----------
// B fragment-ordered => each 32-K chunk is a LINEAR 16 KB block, double-buffered in LDS.
// A-frags are PRELOADED by the caller (af[8], 32 VGPR) so the kc loop has ZERO global
// loads: pre-hoist, each chunk serialized on a ~500cy af load (the only global op left
// after B moved to LDS). Occupancy-free: 512-thread blocks are 1 block/CU regardless.
static __device__ __forceinline__ void gemm_tile_lds(const short8 (&af)[8],
                                                     const short* __restrict__ Bt,
                                                     short (&Bs)[2][8192],
                                                     int tid, int lane,
                                                     f32x4 (&acc)[16])
{
    #pragma unroll
    for (int nt = 0; nt < 16; ++nt) acc[nt] = (f32x4){0.f, 0.f, 0.f, 0.f};
    {
        const short8* src = (const short8*)Bt + tid;
        short8* dst = (short8*)Bs[0] + tid;
        dst[0] = src[0]; dst[512] = src[512];
    }
    __syncthreads();
    #pragma unroll
    for (int kc = 0; kc < 8; ++kc) {
        short8 stg0, stg1;
        if (kc < 7) {
            const short8* src = (const short8*)(Bt + (size_t)(kc + 1) * 8192) + tid;
            stg0 = src[0]; stg1 = src[512];
        }
        const short* Bl = Bs[kc & 1] + lane * 8;
        #pragma unroll
        for (int nt = 0; nt < 16; ++nt) {
            const short8 bf = *(const short8*)(Bl + nt * 512);
            acc[nt] = __builtin_amdgcn_mfma_f32_16x16x32_bf16(af[kc], bf, acc[nt], 0, 0, 0);
        }
        if (kc < 7) {
            short8* dst = (short8*)Bs[(kc + 1) & 1] + tid;
            dst[0] = stg0; dst[512] = stg1;
        }
        __syncthreads();
    }
}

static __device__ __forceinline__ void load_afrag(const short* __restrict__ A,
                                                  int rowA, int quad, short8 (&af)[8])
{
    const short* Ar = A + (size_t)rowA * D + quad * 8;
    #pragma unroll
    for (int kc = 0; kc < 8; ++kc) af[kc] = *(const short8*)(Ar + kc * 32);
}

// ---------- GEMM + bias + residual + LayerNorm, writes fp32 + bf16 ----------
__global__ __launch_bounds__(512)
void gemm_res_ln_kernel(const short* __restrict__ A, const short* __restrict__ Bt,
                        const float* __restrict__ bias, const float* __restrict__ resid,
                        const float* __restrict__ gam, const float* __restrict__ bet,
                        float* __restrict__ xout, short* __restrict__ xbout)
{
    const int tid = threadIdx.x, wave = tid >> 6, lane = tid & 63;
    const int l16 = lane & 15, quad = lane >> 4;
    const int row0 = blockIdx.x * 128 + wave * 16;
    __shared__ __align__(16) short Bs[2][8192];
    short8 af[8];
    load_afrag(A, row0 + l16, quad, af);     // issues before Bs staging+barrier -> overlapped
    f32x4 acc[16];
    gemm_tile_lds(af, Bt, Bs, tid, lane, acc);

    #pragma unroll
    for (int nt = 0; nt < 16; ++nt) {
        const int col = nt * 16 + l16;
        const float bl = bias[col];
        #pragma unroll
        for (int r = 0; r < 4; ++r)
            acc[nt][r] += bl + resid[(size_t)(row0 + quad * 4 + r) * D + col];
    }
    float mu[4], rstd[4];
    #pragma unroll
    for (int r = 0; r < 4; ++r) {
        float s = 0.f;
        #pragma unroll
        for (int nt = 0; nt < 16; ++nt) s += acc[nt][r];
        s += __shfl_xor(s, 1, 64); s += __shfl_xor(s, 2, 64);
        s += __shfl_xor(s, 4, 64); s += __shfl_xor(s, 8, 64);
        mu[r] = s * (1.f / D);
        float q = 0.f;
        #pragma unroll
        for (int nt = 0; nt < 16; ++nt) { const float d = acc[nt][r] - mu[r]; q = fmaf(d, d, q); }
        q += __shfl_xor(q, 1, 64); q += __shfl_xor(q, 2, 64);
        q += __shfl_xor(q, 4, 64); q += __shfl_xor(q, 8, 64);
        rstd[r] = rsqrtf(q * (1.f / D) + LN_EPS);
    }
    #pragma unroll
    for (int nt = 0; nt < 16; ++nt) {
        const int col = nt * 16 + l16;
        const float g = gam[col], be = bet[col];
        #pragma unroll
        for (int r = 0; r < 4; ++r) {
            const size_t idx = (size_t)(row0 + quad * 4 + r) * D + col;
            const float o = (acc[nt][r] - mu[r]) * rstd[r] * g + be;
            xout[idx] = o;
            xbout[idx] = f2bf(o);
        }
    }
}

// ---------- GEMM + bias + relu -> bf16 ----------
__global__ __launch_bounds__(512)
void gemm_relu_kernel(const short* __restrict__ A, const short* __restrict__ Bt,
                      const float* __restrict__ bias, short* __restrict__ hb)
{
    const int tid = threadIdx.x, wave = tid >> 6, lane = tid & 63;
    const int l16 = lane & 15, quad = lane >> 4;
    const int row0 = blockIdx.x * 128 + wave * 16;
    __shared__ __align__(16) short Bs[2][8192];
    short8 af[8];
    load_afrag(A, row0 + l16, quad, af);
    f32x4 acc[16];
    gemm_tile_lds(af, Bt, Bs, tid, lane, acc);
    #pragma unroll
    for (int nt = 0; nt < 16; ++nt) {
        const int col = nt * 16 + l16;
        const float bl = bias[col];
        #pragma unroll
        for (int r = 0; r < 4; ++r)
            hb[(size_t)(row0 + quad * 4 + r) * D + col] = f2bf(fmaxf(acc[nt][r] + bl, 0.f));
    }
}

// ---------- QKV: three GEMMs sharing ONE A-frag load. Q,K padded; V row-major ----------
__global__ __launch_bounds__(512)
void qkv_gemm_kernel(const short* __restrict__ A, const short* __restrict__ Wt,
                     short* __restrict__ Qb, short* __restrict__ Kb,
                     short* __restrict__ Vb, int S)
{
    const int tid = threadIdx.x, wave = tid >> 6, lane = tid & 63;
    const int l16 = lane & 15, quad = lane >> 4;
    const int row0 = blockIdx.x * 128 + wave * 16;
    __shared__ __align__(16) short Bs[2][8192];
    int bb[4], ss[4];
    #pragma unroll
    for (int r = 0; r < 4; ++r) {
        const int row = row0 + quad * 4 + r;
        bb[r] = row / S; ss[r] = row - bb[r] * S;
    }
    short8 af[8];
    load_afrag(A, row0 + l16, quad, af);     // shared across all three GEMMs
    #pragma unroll 1
    for (int m = 0; m < 3; ++m) {
        f32x4 acc[16];
        gemm_tile_lds(af, Wt + (size_t)m * 65536, Bs, tid, lane, acc);
        #pragma unroll
        for (int nt = 0; nt < 16; ++nt) {
            const int col = nt * 16 + l16, h = col >> 6, dim = col & 63;
            #pragma unroll
            for (int r = 0; r < 4; ++r) {
                const int bh = bb[r] * H + h;
                const short v = f2bf(acc[nt][r]);
                if (m == 0)      Qb[((size_t)bh * SPAD + ss[r]) * 64 + dim] = v;
                else if (m == 1) Kb[((size_t)bh * SPAD + ss[r]) * 64 + dim] = v;
                else             Vb[((size_t)bh * S + ss[r]) * 64 + dim] = v;   // row-major, unpadded
            }
        }
    }
}

// ---------- V transpose: [bh][s][64] -> Vt[bh][64][pos] (permuted, padded, zero tail) ----------
__global__ __launch_bounds__(256)
void vt_transpose_kernel(const short* __restrict__ Vb, short* __restrict__ Vt, int S)
{
    const int bh = blockIdx.y;
    const int s0 = blockIdx.x * 64;
    const int t = threadIdx.x;
    __shared__ short T[64][72];
    {
        const int r = t >> 2, c = (t & 3) * 16;
        const int s = s0 + r;
        short8 v0 = (short8){0,0,0,0,0,0,0,0}, v1 = (short8){0,0,0,0,0,0,0,0};
        if (s < S) {
            const short* src = Vb + ((size_t)bh * S + s) * 64 + c;
            v0 = *(const short8*)src;
            v1 = *(const short8*)(src + 8);
        }
        *(short8*)&T[r][c] = v0;
        *(short8*)&T[r][c + 8] = v1;
    }
    __syncthreads();
    {
        const int dim = t >> 2, g = t & 3;
        int w[8];
        #pragma unroll
        for (int j = 0; j < 8; ++j) {
            const int d = g * 8 + j;                       // dword index 0..31 in this 64-span
            const int k0 = ((d >> 4) << 5) | (d & 15);     // key row in tile (pair partner +16)
            const unsigned lo = (unsigned short)T[k0][dim];
            const unsigned hi = (unsigned short)T[k0 + 16][dim];
            w[j] = (int)(lo | (hi << 16));
        }
        int* dst = (int*)(Vt + ((size_t)bh * 64 + dim) * SPAD + s0) + g * 8;
        *(i32x4*)dst = (i32x4){w[0], w[1], w[2], w[3]};
        *(i32x4*)(dst + 4) = (i32x4){w[4], w[5], w[6], w[7]};
    }
}

// ---------------- MFMA attention: one block per (b,h), K+V in registers, Q pipelined ----------------
// grid = 512 (one per bh), 4 waves, 32 q-tile iterations. Register-capped at 2 waves/SIMD
// (kf+vf = 128 regs by design), so the lever is the per-iter serial chain: the next
// q-tile's Q loads issue right after the current QK MFMAs (aq dead) and complete during
// exp+pack+barrier+PV -> the only global load in the loop leaves the critical path.
__global__ __launch_bounds__(256, 2)
void attn_kernel(const short* __restrict__ Qb, const short* __restrict__ Kb,
                 const short* __restrict__ Vt, const float* __restrict__ gc,
                 const float* __restrict__ awl, const int* __restrict__ Kp,
                 short* __restrict__ out, int S)
{
    const int bh = blockIdx.x;
    const int b = bh >> 2, h = bh & 3;
    const int tid = threadIdx.x;
    const int wave = tid >> 6, lane = tid & 63;
    const int l16 = lane & 15, quad = lane >> 4;
    const int NK = S - 1;
    const int Kc = Kp[0];
    const float rKc = 1.0f / (float)Kc;
    const float g0 = tanhf(awl[h * 6]);

    __shared__ __align__(16) float Lw[2][16][4];
    __shared__ __align__(16) short Pb[2][16][PBS];

    const int kb0 = wave * 128;
    const short* Kbh = Kb + (size_t)bh * SPAD * 64;
    const short* Vbh = Vt + (size_t)bh * 64 * SPAD;
    const float* gch = gc + (size_t)h * (21 * 512);
    const int dsl = wave * 16;
    const short* Vrow = Vbh + (size_t)(dsl + l16) * SPAD + quad * 8;

    // ---- hoisted: wave's 128-key K-span (64 VGPR) + 16-dim V-slice (64 VGPR) ----
    short8 kf[16];
    #pragma unroll
    for (int c = 0; c < 4; ++c) {
        const size_t kr = (size_t)(kb0 + c * 32 + l16) * 64 + quad * 8;
        kf[4 * c + 0] = *(const short8*)(Kbh + kr);
        kf[4 * c + 1] = *(const short8*)(Kbh + kr + 32);
        kf[4 * c + 2] = *(const short8*)(Kbh + kr + 16 * 64);
        kf[4 * c + 3] = *(const short8*)(Kbh + kr + 16 * 64 + 32);
    }
    short8 vf[16];
    #pragma unroll
    for (int ks = 0; ks < 16; ++ks) vf[ks] = *(const short8*)(Vrow + ks * 32);

    // ---- Q for iteration 0 ----
    const size_t qbase = (size_t)bh * SPAD * 64;
    short8 aq0 = *(const short8*)(Qb + qbase + (size_t)l16 * 64 + quad * 8);
    short8 aq1 = *(const short8*)(Qb + qbase + (size_t)l16 * 64 + 32 + quad * 8);

    #pragma unroll 1
    for (int it = 0; it < 32; ++it) {
        const int q0 = it << 4;
        const int bsel = it & 1;

        // ---- QK^T from registers ----
        f32x4 sc[8];
        #pragma unroll
        for (int c = 0; c < 4; ++c) {
            const int kbase = kb0 + c * 32;
            f32x4 s0 = (f32x4){0.f, 0.f, 0.f, 0.f}, s1 = (f32x4){0.f, 0.f, 0.f, 0.f};
            s0 = __builtin_amdgcn_mfma_f32_16x16x32_bf16(aq0, kf[4 * c + 0], s0, 0, 0, 0);
            s0 = __builtin_amdgcn_mfma_f32_16x16x32_bf16(aq1, kf[4 * c + 1], s0, 0, 0, 0);
            s1 = __builtin_amdgcn_mfma_f32_16x16x32_bf16(aq0, kf[4 * c + 2], s1, 0, 0, 0);
            s1 = __builtin_amdgcn_mfma_f32_16x16x32_bf16(aq1, kf[4 * c + 3], s1, 0, 0, 0);
            if (kbase + 32 > S) {
                const bool v0 = (kbase + l16) < S, v1 = (kbase + 16 + l16) < S;
                #pragma unroll
                for (int r = 0; r < 4; ++r) {
                    s0[r] = v0 ? s0[r] : -INFINITY;
                    s1[r] = v1 ? s1[r] : -INFINITY;
                }
            }
            sc[2 * c] = s0; sc[2 * c + 1] = s1;
        }

        // ---- pipeline: issue NEXT iteration's Q now (aq dead; wait lands after PV).
        // it=31 reads the first rows of Kb (contiguous allocation) - harmless, unused.
        const size_t nqrow = qbase + (size_t)(q0 + 16 + l16) * 64;
        const short8 nq0 = *(const short8*)(Qb + nqrow + quad * 8);
        const short8 nq1 = *(const short8*)(Qb + nqrow + 32 + quad * 8);

        // ---- gate prefetch from class table (L2-hot) ----
        int dq[4]; const float* gr[4];
        #pragma unroll
        for (int r = 0; r < 4; ++r) {
            const int q = q0 + quad * 4 + r;
            const bool qs = q < NK;
            const int cls = qs ? idivf(q, Kc, rKc) : 20;
            gr[r] = gch + (size_t)cls * 512 + kb0 + 2 * l16;
            dq[r] = qs ? q : -1;
        }
        f32x2 gpre[16];
        #pragma unroll
        for (int r = 0; r < 4; ++r)
            #pragma unroll
            for (int c = 0; c < 4; ++c)
                gpre[r * 4 + c] = *(const f32x2*)(gr[r] + c * 32);

        // ---- exp2 + partial row sums (this wave's 128 keys) ----
        float ls[4] = {0.f, 0.f, 0.f, 0.f};
        #pragma unroll
        for (int j = 0; j < 8; ++j) {
            #pragma unroll
            for (int r = 0; r < 4; ++r) {
                const float e = exp2_fast(sc[j][r]);
                sc[j][r] = e;
                ls[r] += e;
            }
        }
        #pragma unroll
        for (int r = 0; r < 4; ++r) {
            ls[r] += __shfl_xor(ls[r], 1, 64);
            ls[r] += __shfl_xor(ls[r], 2, 64);
            ls[r] += __shfl_xor(ls[r], 4, 64);
            ls[r] += __shfl_xor(ls[r], 8, 64);
        }
        if (l16 == 0) {
            #pragma unroll
            for (int r = 0; r < 4; ++r) Lw[bsel][quad * 4 + r][wave] = ls[r];
        }

        // ---- gate (diagonal cndmask fix) + cvt_pk -> packed b32 P writes ----
        #pragma unroll
        for (int c = 0; c < 4; ++c) {
            const int key0 = kb0 + c * 32 + l16, key1 = key0 + 16;
            #pragma unroll
            for (int r = 0; r < 4; ++r) {
                const f32x2 g = gpre[r * 4 + c];
                const float gx = (key0 == dq[r]) ? g0 : g.x;
                const float gy = (key1 == dq[r]) ? g0 : g.y;
                const float p0 = sc[2 * c][r] * gx;
                const float p1 = sc[2 * c + 1][r] * gy;
                unsigned int pk;
                asm("v_cvt_pk_bf16_f32 %0, %1, %2" : "=v"(pk) : "v"(p0), "v"(p1));
                *(unsigned int*)(&Pb[bsel][quad * 4 + r][kb0 + c * 32 + 2 * l16]) = pk;
            }
        }
        __syncthreads();

        // ---- PV: P from LDS (issue all 16 reads), V from registers ----
        const short* Prow = &Pb[bsel][l16][quad * 8];
        short8 ap[16];
        #pragma unroll
        for (int ks = 0; ks < 16; ++ks) ap[ks] = *(const short8*)(Prow + ks * 32);
        f32x4 O0 = (f32x4){0.f, 0.f, 0.f, 0.f}, O1 = (f32x4){0.f, 0.f, 0.f, 0.f};
        #pragma unroll
        for (int ks = 0; ks < 16; ks += 2) {
            O0 = __builtin_amdgcn_mfma_f32_16x16x32_bf16(ap[ks], vf[ks], O0, 0, 0, 0);
            O1 = __builtin_amdgcn_mfma_f32_16x16x32_bf16(ap[ks + 1], vf[ks + 1], O1, 0, 0, 0);
        }
        const f32x4 O = O0 + O1;

        // ---- epilogue: divide by global l, write bf16 ----
        #pragma unroll
        for (int r = 0; r < 4; ++r) {
            const int q = quad * 4 + r;
            const int s = q0 + q;
            if (s < S) {
                const f32x4 lv = *(const f32x4*)Lw[bsel][q];
                const float lq = (lv[0] + lv[1]) + (lv[2] + lv[3]);
                out[((size_t)b * S + s) * D + h * 64 + dsl + l16] =
                    f2bf(O[r] * __builtin_amdgcn_rcpf(lq));
            }
        }

        aq0 = nq0; aq1 = nq1;
    }
}

extern "C" void kernel_launch(void* const* d_in, const int* in_sizes, int n_in,
                              void* d_out, int out_size, void* d_ws, size_t ws_size,
                              hipStream_t stream)
{
    const float* samples = (const float*)d_in[0];
    const float* Wq      = (const float*)d_in[1];
    const float* Wk      = (const float*)d_in[2];
    const float* Wv      = (const float*)d_in[3];
    const float* attn_w  = (const float*)d_in[4];
    const float* fc_w    = (const float*)d_in[5];
    const float* fc_b    = (const float*)d_in[6];
    const float* mha_g   = (const float*)d_in[7];
    const float* mha_b   = (const float*)d_in[8];
    const float* w1      = (const float*)d_in[9];
    const float* b1      = (const float*)d_in[10];
    const float* w2      = (const float*)d_in[11];
    const float* b2      = (const float*)d_in[12];
    const float* dg      = (const float*)d_in[13];
    const float* db      = (const float*)d_in[14];
    const float* ow      = (const float*)d_in[15];
    const float* ob      = (const float*)d_in[16];
    const float* og      = (const float*)d_in[17];
    const float* obeta   = (const float*)d_in[18];
    const int*   Kp      = (const int*)d_in[20];

    const int Bsz = 128;
    const int S = in_sizes[0] / (Bsz * D);   // 501
    const int rows = Bsz * S;                // 64128
    const size_t n_el = (size_t)rows * D;
    const size_t n_pad = (size_t)Bsz * H * SPAD * 64;

    float* x   = (float*)d_out;
    short* xb  = (short*)d_ws;               // bf16 activations [rows][D]
    short* aob = xb + n_el;                  // attn out bf16; aliased as Vb and later hb
    short* hb  = aob;
    short* Vb  = aob;                        // row-major V [B*H][S][64], exactly n_el shorts
    short* Qb  = aob + n_el;                 // [B*H][512][64]
    short* Kb  = Qb + n_pad;                 // [B*H][512][64]
    short* Vt  = Kb + n_pad;                 // [B*H][64][512] (key-permuted)
    short* wts = Vt + n_pad;
    float* gcls = (float*)(wts + (size_t)NMAT * 65536);   // [L][H][21][512] f32, 344 KB

    PackArgs pa;
    for (int l = 0; l < 2; ++l) {
        const size_t wo = (size_t)l * 65536;
        pa.src[l*6 + 0] = Wq + wo;   pa.scale[l*6 + 0] = 0.125f * LOG2E;  // temp + log2e fold
        pa.src[l*6 + 1] = Wk + wo;   pa.scale[l*6 + 1] = 1.f;
        pa.src[l*6 + 2] = Wv + wo;   pa.scale[l*6 + 2] = 1.f;
        pa.src[l*6 + 3] = fc_w + wo; pa.scale[l*6 + 3] = 1.f;
        pa.src[l*6 + 4] = w1 + wo;   pa.scale[l*6 + 4] = 1.f;
        pa.src[l*6 + 5] = w2 + wo;   pa.scale[l*6 + 5] = 1.f;
    }
    pa.src[12] = ow; pa.scale[12] = 1.f;
    pa.dst = wts;
    pack_kernel<<<dim3(256, NMAT), 256, 0, stream>>>(pa);

    gate_cls_kernel<<<dim3(42, H, 2), 256, 0, stream>>>(attn_w, Kp, gcls, S);

    cast_kernel<<<(int)((n_el / 4 + 255) / 256), 256, 0, stream>>>(samples, xb, (long)n_el);

    const int gblocks = rows / 128;          // 501
    for (int l = 0; l < 2; ++l) {
        short* wl = wts + (size_t)l * 6 * 65536;
        const float* layer_in = (l == 0) ? samples : x;   // fp32 residual source
        qkv_gemm_kernel<<<gblocks, 512, 0, stream>>>(xb, wl, Qb, Kb, Vb, S);
        vt_transpose_kernel<<<dim3(8, Bsz * H), 256, 0, stream>>>(Vb, Vt, S);
        attn_kernel<<<Bsz * H, 256, 0, stream>>>(Qb, Kb, Vt,
                                              gcls + (size_t)l * H * 21 * 512,
                                              attn_w + (size_t)l * H * 6, Kp, aob, S);
        gemm_res_ln_kernel<<<gblocks, 512, 0, stream>>>(aob, wl + 3 * 65536,
                                              fc_b + (size_t)l * D, layer_in,
                                              mha_g + (size_t)l * D, mha_b + (size_t)l * D,
                                              x, xb);
        gemm_relu_kernel<<<gblocks, 512, 0, stream>>>(xb, wl + 4 * 65536,
                                              b1 + (size_t)l * D, hb);
        gemm_res_ln_kernel<<<gblocks, 512, 0, stream>>>(hb, wl + 5 * 65536,
                                              b2 + (size_t)l * D, x,
                                              dg + (size_t)l * D, db + (size_t)l * D,
                                              x, xb);
    }
    gemm_res_ln_kernel<<<gblocks, 512, 0, stream>>>(xb, wts + 12 * 65536,
                                              ob, samples, og, obeta, x, xb);
}

// Round 9
// 742.900 us; speedup vs baseline: 2.2534x; 1.0240x over previous
//
#include <hip/hip_runtime.h>
#include <cstdint>
#include <cstddef>
#include <cmath>

#define D 256
#define H 4
#define LN_EPS 1e-5f
#define SPAD 512
#define NMAT 13
#define PBS 520   // Pb row stride in shorts: 1040 B = 65*16 (aligned), 260 words
#define LOG2E 1.44269504088896340736f

typedef __attribute__((ext_vector_type(8))) short short8;
typedef __attribute__((ext_vector_type(4))) short short4v;
typedef __attribute__((ext_vector_type(4))) float f32x4;
typedef __attribute__((ext_vector_type(2))) float f32x2;
typedef __attribute__((ext_vector_type(4))) int i32x4;

static __device__ __forceinline__ short f2bf(float f) {
    union { float f; unsigned u; } a; a.f = f;
    unsigned r = a.u + 0x7fffu + ((a.u >> 16) & 1u);
    return (short)(r >> 16);
}

static __device__ __forceinline__ float exp2_fast(float x) {
#if __has_builtin(__builtin_amdgcn_exp2f)
    return __builtin_amdgcn_exp2f(x);
#else
    float r; asm("v_exp_f32 %0, %1" : "=v"(r) : "v"(x)); return r;
#endif
}

// exact int divide by small runtime divisor via float reciprocal + correction
static __device__ __forceinline__ int idivf(int x, int Kc, float rKc) {
    int q = (int)((float)x * rKc);
    q -= (q * Kc > x) ? 1 : 0;
    q += ((q + 1) * Kc <= x) ? 1 : 0;
    return q;
}

// ---------- pack fp32 W[k][n] -> bf16 fragment-ordered B ----------
struct PackArgs { const float* src[NMAT]; float scale[NMAT]; short* dst; };

__global__ __launch_bounds__(256)
void pack_kernel(PackArgs pa)
{
    const int mat = blockIdx.y;
    const int el = blockIdx.x * 256 + threadIdx.x;
    const int n = el & 255, k = el >> 8;
    const int nt = n >> 4, l16 = n & 15;
    const int kc = k >> 5, qd = (k >> 3) & 3, j = k & 7;
    const size_t didx = (((size_t)(kc * 16 + nt) * 64) + qd * 16 + l16) * 8 + j;
    pa.dst[(size_t)mat * 65536 + didx] =
        f2bf(pa.src[mat][(size_t)k * 256 + n] * pa.scale[mat]);
}

// ---------- gate CLASS table: gc[l][h][cls][pos], cls = q/Kc (0..19) or 20 (query row) ----------
// pos is the PERMUTED key index: within each 32-block, key = 16*(pos&1) + ((pos>>1)&15).
// Diagonal (key==q -> g0) is NOT baked; fixed in attn with a cndmask.
__global__ __launch_bounds__(256)
void gate_cls_kernel(const float* __restrict__ aw, const int* __restrict__ Kp,
                     float* __restrict__ gc, int S)
{
    const int idx = blockIdx.x * 256 + threadIdx.x;   // cls*512 + pos, 21*512 = 10752
    const int h = blockIdx.y, l = blockIdx.z;
    const int cls = idx >> 9, pos = idx & 511;
    const int key = (pos & ~31) | ((pos & 1) << 4) | ((pos >> 1) & 15);
    const int NK = S - 1;
    const int Kc = Kp[0];
    int cat;
    if (cls < 20) cat = (key == NK) ? 3 : ((key < NK && key / Kc == cls) ? 1 : 2);
    else          cat = (key == NK) ? 5 : 4;
    gc[((size_t)(l * H + h) * 21 + cls) * 512 + pos] = tanhf(aw[(l * H + h) * 6 + cat]);
}

// ---------- bf16 cast only (fp32 copy dropped: layer-0 residual reads samples directly) ----------
__global__ __launch_bounds__(256)
void cast_kernel(const float* __restrict__ x, short* __restrict__ xb, long n)
{
    const long i = ((long)blockIdx.x * 256 + threadIdx.x) * 4;
    if (i >= n) return;
    const f32x4 v = *(const f32x4*)(x + i);
    short4v o;
    o.x = f2bf(v.x); o.y = f2bf(v.y); o.z = f2bf(v.z); o.w = f2bf(v.w);
    *(short4v*)(xb + i) = o;
}

// ---------- MFMA mainloop, 512-thread blocks: 8 waves x 16 rows, 256 cols, K=256 ----------
// B fragment-ordered => each 32-K chunk is a LINEAR 16 KB block, double-buffered in LDS.
// af loaded per-chunk inside the loop (1 short8 live; round-8 hoist was reg-cost for no
// gain). With __launch_bounds__(512,2) the whole kernel fits 128 regs -> 2 blocks/CU:
// the 501-block grid runs in ONE residency round and barrier stalls of one block hide
// under the other block's MFMAs.
static __device__ __forceinline__ void gemm_tile_lds(const short* __restrict__ A,
                                                     const short* __restrict__ Bt,
                                                     short (&Bs)[2][8192],
                                                     int rowA, int tid, int lane, int quad,
                                                     f32x4 (&acc)[16])
{
    const short* Ar = A + (size_t)rowA * D + quad * 8;
    #pragma unroll
    for (int nt = 0; nt < 16; ++nt) acc[nt] = (f32x4){0.f, 0.f, 0.f, 0.f};
    {
        const short8* src = (const short8*)Bt + tid;
        short8* dst = (short8*)Bs[0] + tid;
        dst[0] = src[0]; dst[512] = src[512];
    }
    __syncthreads();
    #pragma unroll
    for (int kc = 0; kc < 8; ++kc) {
        short8 stg0, stg1;
        if (kc < 7) {
            const short8* src = (const short8*)(Bt + (size_t)(kc + 1) * 8192) + tid;
            stg0 = src[0]; stg1 = src[512];
        }
        const short8 af = *(const short8*)(Ar + kc * 32);
        const short* Bl = Bs[kc & 1] + lane * 8;
        #pragma unroll
        for (int nt = 0; nt < 16; ++nt) {
            const short8 bf = *(const short8*)(Bl + nt * 512);
            acc[nt] = __builtin_amdgcn_mfma_f32_16x16x32_bf16(af, bf, acc[nt], 0, 0, 0);
        }
        if (kc < 7) {
            short8* dst = (short8*)Bs[(kc + 1) & 1] + tid;
            dst[0] = stg0; dst[512] = stg1;
        }
        __syncthreads();
    }
}

// ---------- GEMM + bias + residual + LayerNorm, writes fp32 + bf16 ----------
__global__ __launch_bounds__(512, 2)
void gemm_res_ln_kernel(const short* __restrict__ A, const short* __restrict__ Bt,
                        const float* __restrict__ bias, const float* __restrict__ resid,
                        const float* __restrict__ gam, const float* __restrict__ bet,
                        float* __restrict__ xout, short* __restrict__ xbout)
{
    const int tid = threadIdx.x, wave = tid >> 6, lane = tid & 63;
    const int l16 = lane & 15, quad = lane >> 4;
    const int row0 = blockIdx.x * 128 + wave * 16;
    __shared__ __align__(16) short Bs[2][8192];
    f32x4 acc[16];
    gemm_tile_lds(A, Bt, Bs, row0 + l16, tid, lane, quad, acc);

    #pragma unroll
    for (int nt = 0; nt < 16; ++nt) {
        const int col = nt * 16 + l16;
        const float bl = bias[col];
        #pragma unroll
        for (int r = 0; r < 4; ++r)
            acc[nt][r] += bl + resid[(size_t)(row0 + quad * 4 + r) * D + col];
    }
    float mu[4], rstd[4];
    #pragma unroll
    for (int r = 0; r < 4; ++r) {
        float s = 0.f;
        #pragma unroll
        for (int nt = 0; nt < 16; ++nt) s += acc[nt][r];
        s += __shfl_xor(s, 1, 64); s += __shfl_xor(s, 2, 64);
        s += __shfl_xor(s, 4, 64); s += __shfl_xor(s, 8, 64);
        mu[r] = s * (1.f / D);
        float q = 0.f;
        #pragma unroll
        for (int nt = 0; nt < 16; ++nt) { const float d = acc[nt][r] - mu[r]; q = fmaf(d, d, q); }
        q += __shfl_xor(q, 1, 64); q += __shfl_xor(q, 2, 64);
        q += __shfl_xor(q, 4, 64); q += __shfl_xor(q, 8, 64);
        rstd[r] = rsqrtf(q * (1.f / D) + LN_EPS);
    }
    #pragma unroll
    for (int nt = 0; nt < 16; ++nt) {
        const int col = nt * 16 + l16;
        const float g = gam[col], be = bet[col];
        #pragma unroll
        for (int r = 0; r < 4; ++r) {
            const size_t idx = (size_t)(row0 + quad * 4 + r) * D + col;
            const float o = (acc[nt][r] - mu[r]) * rstd[r] * g + be;
            xout[idx] = o;
            xbout[idx] = f2bf(o);
        }
    }
}

// ---------- GEMM + bias + relu -> bf16 ----------
__global__ __launch_bounds__(512, 2)
void gemm_relu_kernel(const short* __restrict__ A, const short* __restrict__ Bt,
                      const float* __restrict__ bias, short* __restrict__ hb)
{
    const int tid = threadIdx.x, wave = tid >> 6, lane = tid & 63;
    const int l16 = lane & 15, quad = lane >> 4;
    const int row0 = blockIdx.x * 128 + wave * 16;
    __shared__ __align__(16) short Bs[2][8192];
    f32x4 acc[16];
    gemm_tile_lds(A, Bt, Bs, row0 + l16, tid, lane, quad, acc);
    #pragma unroll
    for (int nt = 0; nt < 16; ++nt) {
        const int col = nt * 16 + l16;
        const float bl = bias[col];
        #pragma unroll
        for (int r = 0; r < 4; ++r)
            hb[(size_t)(row0 + quad * 4 + r) * D + col] = f2bf(fmaxf(acc[nt][r] + bl, 0.f));
    }
}

// ---------- QKV: three GEMMs. Q,K padded layouts; V ROW-MAJOR (coalesced) ----------
__global__ __launch_bounds__(512, 2)
void qkv_gemm_kernel(const short* __restrict__ A, const short* __restrict__ Wt,
                     short* __restrict__ Qb, short* __restrict__ Kb,
                     short* __restrict__ Vb, int S)
{
    const int tid = threadIdx.x, wave = tid >> 6, lane = tid & 63;
    const int l16 = lane & 15, quad = lane >> 4;
    const int row0 = blockIdx.x * 128 + wave * 16;
    __shared__ __align__(16) short Bs[2][8192];
    int bb[4], ss[4];
    #pragma unroll
    for (int r = 0; r < 4; ++r) {
        const int row = row0 + quad * 4 + r;
        bb[r] = row / S; ss[r] = row - bb[r] * S;
    }
    #pragma unroll 1
    for (int m = 0; m < 3; ++m) {
        f32x4 acc[16];
        gemm_tile_lds(A, Wt + (size_t)m * 65536, Bs, row0 + l16, tid, lane, quad, acc);
        #pragma unroll
        for (int nt = 0; nt < 16; ++nt) {
            const int col = nt * 16 + l16, h = col >> 6, dim = col & 63;
            #pragma unroll
            for (int r = 0; r < 4; ++r) {
                const int bh = bb[r] * H + h;
                const short v = f2bf(acc[nt][r]);
                if (m == 0)      Qb[((size_t)bh * SPAD + ss[r]) * 64 + dim] = v;
                else if (m == 1) Kb[((size_t)bh * SPAD + ss[r]) * 64 + dim] = v;
                else             Vb[((size_t)bh * S + ss[r]) * 64 + dim] = v;   // row-major, unpadded
            }
        }
    }
}

// ---------- V transpose: [bh][s][64] -> Vt[bh][64][pos] (permuted, padded, zero tail) ----------
__global__ __launch_bounds__(256)
void vt_transpose_kernel(const short* __restrict__ Vb, short* __restrict__ Vt, int S)
{
    const int bh = blockIdx.y;
    const int s0 = blockIdx.x * 64;
    const int t = threadIdx.x;
    __shared__ short T[64][72];
    {
        const int r = t >> 2, c = (t & 3) * 16;
        const int s = s0 + r;
        short8 v0 = (short8){0,0,0,0,0,0,0,0}, v1 = (short8){0,0,0,0,0,0,0,0};
        if (s < S) {
            const short* src = Vb + ((size_t)bh * S + s) * 64 + c;
            v0 = *(const short8*)src;
            v1 = *(const short8*)(src + 8);
        }
        *(short8*)&T[r][c] = v0;
        *(short8*)&T[r][c + 8] = v1;
    }
    __syncthreads();
    {
        const int dim = t >> 2, g = t & 3;
        int w[8];
        #pragma unroll
        for (int j = 0; j < 8; ++j) {
            const int d = g * 8 + j;                       // dword index 0..31 in this 64-span
            const int k0 = ((d >> 4) << 5) | (d & 15);     // key row in tile (pair partner +16)
            const unsigned lo = (unsigned short)T[k0][dim];
            const unsigned hi = (unsigned short)T[k0 + 16][dim];
            w[j] = (int)(lo | (hi << 16));
        }
        int* dst = (int*)(Vt + ((size_t)bh * 64 + dim) * SPAD + s0) + g * 8;
        *(i32x4*)dst = (i32x4){w[0], w[1], w[2], w[3]};
        *(i32x4*)(dst + 4) = (i32x4){w[4], w[5], w[6], w[7]};
    }
}

// ---------------- MFMA attention: one block per (b,h), K+V in registers, Q pipelined ----------------
// grid = 512 (one per bh), 4 waves, 32 q-tile iterations. Register-capped at 2 waves/SIMD
// (kf+vf = 128 regs by design); next q-tile's Q loads issue right after the current QK
// MFMAs so the only global load in the loop stays off the critical path.
__global__ __launch_bounds__(256, 2)
void attn_kernel(const short* __restrict__ Qb, const short* __restrict__ Kb,
                 const short* __restrict__ Vt, const float* __restrict__ gc,
                 const float* __restrict__ awl, const int* __restrict__ Kp,
                 short* __restrict__ out, int S)
{
    const int bh = blockIdx.x;
    const int b = bh >> 2, h = bh & 3;
    const int tid = threadIdx.x;
    const int wave = tid >> 6, lane = tid & 63;
    const int l16 = lane & 15, quad = lane >> 4;
    const int NK = S - 1;
    const int Kc = Kp[0];
    const float rKc = 1.0f / (float)Kc;
    const float g0 = tanhf(awl[h * 6]);

    __shared__ __align__(16) float Lw[2][16][4];
    __shared__ __align__(16) short Pb[2][16][PBS];

    const int kb0 = wave * 128;
    const short* Kbh = Kb + (size_t)bh * SPAD * 64;
    const short* Vbh = Vt + (size_t)bh * 64 * SPAD;
    const float* gch = gc + (size_t)h * (21 * 512);
    const int dsl = wave * 16;
    const short* Vrow = Vbh + (size_t)(dsl + l16) * SPAD + quad * 8;

    // ---- hoisted: wave's 128-key K-span (64 VGPR) + 16-dim V-slice (64 VGPR) ----
    short8 kf[16];
    #pragma unroll
    for (int c = 0; c < 4; ++c) {
        const size_t kr = (size_t)(kb0 + c * 32 + l16) * 64 + quad * 8;
        kf[4 * c + 0] = *(const short8*)(Kbh + kr);
        kf[4 * c + 1] = *(const short8*)(Kbh + kr + 32);
        kf[4 * c + 2] = *(const short8*)(Kbh + kr + 16 * 64);
        kf[4 * c + 3] = *(const short8*)(Kbh + kr + 16 * 64 + 32);
    }
    short8 vf[16];
    #pragma unroll
    for (int ks = 0; ks < 16; ++ks) vf[ks] = *(const short8*)(Vrow + ks * 32);

    // ---- Q for iteration 0 ----
    const size_t qbase = (size_t)bh * SPAD * 64;
    short8 aq0 = *(const short8*)(Qb + qbase + (size_t)l16 * 64 + quad * 8);
    short8 aq1 = *(const short8*)(Qb + qbase + (size_t)l16 * 64 + 32 + quad * 8);

    #pragma unroll 1
    for (int it = 0; it < 32; ++it) {
        const int q0 = it << 4;
        const int bsel = it & 1;

        // ---- QK^T from registers ----
        f32x4 sc[8];
        #pragma unroll
        for (int c = 0; c < 4; ++c) {
            const int kbase = kb0 + c * 32;
            f32x4 s0 = (f32x4){0.f, 0.f, 0.f, 0.f}, s1 = (f32x4){0.f, 0.f, 0.f, 0.f};
            s0 = __builtin_amdgcn_mfma_f32_16x16x32_bf16(aq0, kf[4 * c + 0], s0, 0, 0, 0);
            s0 = __builtin_amdgcn_mfma_f32_16x16x32_bf16(aq1, kf[4 * c + 1], s0, 0, 0, 0);
            s1 = __builtin_amdgcn_mfma_f32_16x16x32_bf16(aq0, kf[4 * c + 2], s1, 0, 0, 0);
            s1 = __builtin_amdgcn_mfma_f32_16x16x32_bf16(aq1, kf[4 * c + 3], s1, 0, 0, 0);
            if (kbase + 32 > S) {
                const bool v0 = (kbase + l16) < S, v1 = (kbase + 16 + l16) < S;
                #pragma unroll
                for (int r = 0; r < 4; ++r) {
                    s0[r] = v0 ? s0[r] : -INFINITY;
                    s1[r] = v1 ? s1[r] : -INFINITY;
                }
            }
            sc[2 * c] = s0; sc[2 * c + 1] = s1;
        }

        // ---- pipeline: issue NEXT iteration's Q now (aq dead; wait lands after PV).
        // it=31 reads the first rows of Kb (contiguous allocation) - harmless, unused.
        const size_t nqrow = qbase + (size_t)(q0 + 16 + l16) * 64;
        const short8 nq0 = *(const short8*)(Qb + nqrow + quad * 8);
        const short8 nq1 = *(const short8*)(Qb + nqrow + 32 + quad * 8);

        // ---- gate prefetch from class table (L2-hot) ----
        int dq[4]; const float* gr[4];
        #pragma unroll
        for (int r = 0; r < 4; ++r) {
            const int q = q0 + quad * 4 + r;
            const bool qs = q < NK;
            const int cls = qs ? idivf(q, Kc, rKc) : 20;
            gr[r] = gch + (size_t)cls * 512 + kb0 + 2 * l16;
            dq[r] = qs ? q : -1;
        }
        f32x2 gpre[16];
        #pragma unroll
        for (int r = 0; r < 4; ++r)
            #pragma unroll
            for (int c = 0; c < 4; ++c)
                gpre[r * 4 + c] = *(const f32x2*)(gr[r] + c * 32);

        // ---- exp2 + partial row sums (this wave's 128 keys) ----
        float ls[4] = {0.f, 0.f, 0.f, 0.f};
        #pragma unroll
        for (int j = 0; j < 8; ++j) {
            #pragma unroll
            for (int r = 0; r < 4; ++r) {
                const float e = exp2_fast(sc[j][r]);
                sc[j][r] = e;
                ls[r] += e;
            }
        }
        #pragma unroll
        for (int r = 0; r < 4; ++r) {
            ls[r] += __shfl_xor(ls[r], 1, 64);
            ls[r] += __shfl_xor(ls[r], 2, 64);
            ls[r] += __shfl_xor(ls[r], 4, 64);
            ls[r] += __shfl_xor(ls[r], 8, 64);
        }
        if (l16 == 0) {
            #pragma unroll
            for (int r = 0; r < 4; ++r) Lw[bsel][quad * 4 + r][wave] = ls[r];
        }

        // ---- gate (diagonal cndmask fix) + cvt_pk -> packed b32 P writes ----
        #pragma unroll
        for (int c = 0; c < 4; ++c) {
            const int key0 = kb0 + c * 32 + l16, key1 = key0 + 16;
            #pragma unroll
            for (int r = 0; r < 4; ++r) {
                const f32x2 g = gpre[r * 4 + c];
                const float gx = (key0 == dq[r]) ? g0 : g.x;
                const float gy = (key1 == dq[r]) ? g0 : g.y;
                const float p0 = sc[2 * c][r] * gx;
                const float p1 = sc[2 * c + 1][r] * gy;
                unsigned int pk;
                asm("v_cvt_pk_bf16_f32 %0, %1, %2" : "=v"(pk) : "v"(p0), "v"(p1));
                *(unsigned int*)(&Pb[bsel][quad * 4 + r][kb0 + c * 32 + 2 * l16]) = pk;
            }
        }
        __syncthreads();

        // ---- PV: P from LDS (issue all 16 reads), V from registers ----
        const short* Prow = &Pb[bsel][l16][quad * 8];
        short8 ap[16];
        #pragma unroll
        for (int ks = 0; ks < 16; ++ks) ap[ks] = *(const short8*)(Prow + ks * 32);
        f32x4 O0 = (f32x4){0.f, 0.f, 0.f, 0.f}, O1 = (f32x4){0.f, 0.f, 0.f, 0.f};
        #pragma unroll
        for (int ks = 0; ks < 16; ks += 2) {
            O0 = __builtin_amdgcn_mfma_f32_16x16x32_bf16(ap[ks], vf[ks], O0, 0, 0, 0);
            O1 = __builtin_amdgcn_mfma_f32_16x16x32_bf16(ap[ks + 1], vf[ks + 1], O1, 0, 0, 0);
        }
        const f32x4 O = O0 + O1;

        // ---- epilogue: divide by global l, write bf16 ----
        #pragma unroll
        for (int r = 0; r < 4; ++r) {
            const int q = quad * 4 + r;
            const int s = q0 + q;
            if (s < S) {
                const f32x4 lv = *(const f32x4*)Lw[bsel][q];
                const float lq = (lv[0] + lv[1]) + (lv[2] + lv[3]);
                out[((size_t)b * S + s) * D + h * 64 + dsl + l16] =
                    f2bf(O[r] * __builtin_amdgcn_rcpf(lq));
            }
        }

        aq0 = nq0; aq1 = nq1;
    }
}

extern "C" void kernel_launch(void* const* d_in, const int* in_sizes, int n_in,
                              void* d_out, int out_size, void* d_ws, size_t ws_size,
                              hipStream_t stream)
{
    const float* samples = (const float*)d_in[0];
    const float* Wq      = (const float*)d_in[1];
    const float* Wk      = (const float*)d_in[2];
    const float* Wv      = (const float*)d_in[3];
    const float* attn_w  = (const float*)d_in[4];
    const float* fc_w    = (const float*)d_in[5];
    const float* fc_b    = (const float*)d_in[6];
    const float* mha_g   = (const float*)d_in[7];
    const float* mha_b   = (const float*)d_in[8];
    const float* w1      = (const float*)d_in[9];
    const float* b1      = (const float*)d_in[10];
    const float* w2      = (const float*)d_in[11];
    const float* b2      = (const float*)d_in[12];
    const float* dg      = (const float*)d_in[13];
    const float* db      = (const float*)d_in[14];
    const float* ow      = (const float*)d_in[15];
    const float* ob      = (const float*)d_in[16];
    const float* og      = (const float*)d_in[17];
    const float* obeta   = (const float*)d_in[18];
    const int*   Kp      = (const int*)d_in[20];

    const int Bsz = 128;
    const int S = in_sizes[0] / (Bsz * D);   // 501
    const int rows = Bsz * S;                // 64128
    const size_t n_el = (size_t)rows * D;
    const size_t n_pad = (size_t)Bsz * H * SPAD * 64;

    float* x   = (float*)d_out;
    short* xb  = (short*)d_ws;               // bf16 activations [rows][D]
    short* aob = xb + n_el;                  // attn out bf16; aliased as Vb and later hb
    short* hb  = aob;
    short* Vb  = aob;                        // row-major V [B*H][S][64], exactly n_el shorts
    short* Qb  = aob + n_el;                 // [B*H][512][64]
    short* Kb  = Qb + n_pad;                 // [B*H][512][64]
    short* Vt  = Kb + n_pad;                 // [B*H][64][512] (key-permuted)
    short* wts = Vt + n_pad;
    float* gcls = (float*)(wts + (size_t)NMAT * 65536);   // [L][H][21][512] f32, 344 KB

    PackArgs pa;
    for (int l = 0; l < 2; ++l) {
        const size_t wo = (size_t)l * 65536;
        pa.src[l*6 + 0] = Wq + wo;   pa.scale[l*6 + 0] = 0.125f * LOG2E;  // temp + log2e fold
        pa.src[l*6 + 1] = Wk + wo;   pa.scale[l*6 + 1] = 1.f;
        pa.src[l*6 + 2] = Wv + wo;   pa.scale[l*6 + 2] = 1.f;
        pa.src[l*6 + 3] = fc_w + wo; pa.scale[l*6 + 3] = 1.f;
        pa.src[l*6 + 4] = w1 + wo;   pa.scale[l*6 + 4] = 1.f;
        pa.src[l*6 + 5] = w2 + wo;   pa.scale[l*6 + 5] = 1.f;
    }
    pa.src[12] = ow; pa.scale[12] = 1.f;
    pa.dst = wts;
    pack_kernel<<<dim3(256, NMAT), 256, 0, stream>>>(pa);

    gate_cls_kernel<<<dim3(42, H, 2), 256, 0, stream>>>(attn_w, Kp, gcls, S);

    cast_kernel<<<(int)((n_el / 4 + 255) / 256), 256, 0, stream>>>(samples, xb, (long)n_el);

    const int gblocks = rows / 128;          // 501
    for (int l = 0; l < 2; ++l) {
        short* wl = wts + (size_t)l * 6 * 65536;
        const float* layer_in = (l == 0) ? samples : x;   // fp32 residual source
        qkv_gemm_kernel<<<gblocks, 512, 0, stream>>>(xb, wl, Qb, Kb, Vb, S);
        vt_transpose_kernel<<<dim3(8, Bsz * H), 256, 0, stream>>>(Vb, Vt, S);
        attn_kernel<<<Bsz * H, 256, 0, stream>>>(Qb, Kb, Vt,
                                              gcls + (size_t)l * H * 21 * 512,
                                              attn_w + (size_t)l * H * 6, Kp, aob, S);
        gemm_res_ln_kernel<<<gblocks, 512, 0, stream>>>(aob, wl + 3 * 65536,
                                              fc_b + (size_t)l * D, layer_in,
                                              mha_g + (size_t)l * D, mha_b + (size_t)l * D,
                                              x, xb);
        gemm_relu_kernel<<<gblocks, 512, 0, stream>>>(xb, wl + 4 * 65536,
                                              b1 + (size_t)l * D, hb);
        gemm_res_ln_kernel<<<gblocks, 512, 0, stream>>>(hb, wl + 5 * 65536,
                                              b2 + (size_t)l * D, x,
                                              dg + (size_t)l * D, db + (size_t)l * D,
                                              x, xb);
    }
    gemm_res_ln_kernel<<<gblocks, 512, 0, stream>>>(xb, wts + 12 * 65536,
                                              ob, samples, og, obeta, x, xb);
}